// Round 10
// baseline (492.202 us; speedup 1.0000x reference)
//
#include <hip/hip_runtime.h>
#include <cstdint>
#include <cstddef>

// ---------------- problem constants ----------------
#define NNODE      30000
#define FIN        512
#define H1DIM      1024
#define H2DIM      512
#define H3DIM      256
#define HDIM       512          // mu/logvar width
#define HALF_ROWS  15000
#define HALF_ELEMS 7680000u     // 15000*512 (threefry pair offset)
#define PP_ROWS    16
#define PP_BLOCKS  938          // ceil(15000/16)
#define PM_BLOCKS  64           // mid-reduce blocks (15 pp-blocks each)
#define NPANEL     118          // ceil(30000/256) M-panels (BM=256)
#define NSCAN      118          // ceil(30000/256) scan blocks

typedef __attribute__((ext_vector_type(8))) short s16x8;
typedef __attribute__((ext_vector_type(4))) short s16x4;
typedef __attribute__((ext_vector_type(4))) float f32x4;

// bf16 <-> f32 (RNE, matches JAX/torch)
__device__ __forceinline__ short f2bf(float f) {
    uint32_t u = __float_as_uint(f);
    uint32_t r = (u + 0x7FFFu + ((u >> 16) & 1u)) >> 16;
    return (short)r;
}
__device__ __forceinline__ float bf2f(short s) {
    return __uint_as_float(((uint32_t)(uint16_t)s) << 16);
}

// ---------------- threefry2x32 (JAX-exact) ----------------
__device__ __forceinline__ void threefry2x32(uint32_t k0, uint32_t k1,
                                             uint32_t& x0, uint32_t& x1) {
    uint32_t ks0 = k0, ks1 = k1, ks2 = k0 ^ k1 ^ 0x1BD11BDAu;
    const uint32_t R0[4] = {13u, 15u, 26u, 6u};
    const uint32_t R1[4] = {17u, 29u, 16u, 24u};
    x0 += ks0; x1 += ks1;
#pragma unroll
    for (int g = 0; g < 5; ++g) {
        const uint32_t* R = (g & 1) ? R1 : R0;
#pragma unroll
        for (int r = 0; r < 4; ++r) {
            x0 += x1;
            x1 = (x1 << R[r]) | (x1 >> (32u - R[r]));
            x1 ^= x0;
        }
        uint32_t ks_a = (g % 3 == 0) ? ks1 : (g % 3 == 1 ? ks2 : ks0);
        uint32_t ks_b = (g % 3 == 0) ? ks2 : (g % 3 == 1 ? ks0 : ks1);
        x0 += ks_a;
        x1 += ks_b + (uint32_t)(g + 1);
    }
}

__device__ __forceinline__ float jax_normal(uint32_t bits) {
    uint32_t fb = (bits >> 9) | 0x3F800000u;
    float f = __uint_as_float(fb) - 1.0f;
    const float lo = -0.99999994f;
    float u = fmaf(f, 2.0f, lo);
    u = fmaxf(u, lo);
    return 1.41421356237f * erfinvf(u);
}

// ---------------- degree + count ----------------
__global__ void deg_cnt_kernel(const int* __restrict__ row, const float* __restrict__ w,
                               float* __restrict__ deg, int* __restrict__ cnt, int E) {
    int e = blockIdx.x * 256 + threadIdx.x;
    if (e < E) {
        int r = row[e];
        atomicAdd(&deg[r], w[e]);
        atomicAdd(&cnt[r], 1);
    }
}

__global__ void dinv_kernel(const float* __restrict__ deg, float* __restrict__ dinv, int n) {
    int i = blockIdx.x * 256 + threadIdx.x;
    if (i < n) dinv[i] = rsqrtf(deg[i] + 1.0f);
}

// rinv[i] = 1/max(sqrt(ss[i]), 1e-12), in place
__global__ void rsqrt_clamp_kernel(float* __restrict__ ss, int n) {
    int i = blockIdx.x * 256 + threadIdx.x;
    if (i < n) ss[i] = 1.0f / fmaxf(sqrtf(ss[i]), 1e-12f);
}

// ---------------- parallel rowptr build: blocksum -> scan -> write ----------------
__global__ __launch_bounds__(256) void rp_blocksum(const int* __restrict__ cnt,
                                                   int* __restrict__ bsum) {
    __shared__ int sh[256];
    int i = blockIdx.x * 256 + threadIdx.x;
    sh[threadIdx.x] = (i < NNODE) ? cnt[i] : 0;
    __syncthreads();
    for (int o = 128; o; o >>= 1) {
        if (threadIdx.x < o) sh[threadIdx.x] += sh[threadIdx.x + o];
        __syncthreads();
    }
    if (threadIdx.x == 0) bsum[blockIdx.x] = sh[0];
}

__global__ __launch_bounds__(128) void rp_scan(int* __restrict__ bsum, int nb) {
    __shared__ int sh[128];
    int t = threadIdx.x;
    sh[t] = (t < nb) ? bsum[t] : 0;
    __syncthreads();
    for (int o = 1; o < 128; o <<= 1) {
        int v = (t >= o) ? sh[t - o] : 0;
        __syncthreads();
        sh[t] += v;
        __syncthreads();
    }
    if (t < nb) bsum[t] = (t == 0) ? 0 : sh[t - 1];   // exclusive
}

__global__ __launch_bounds__(256) void rp_write(const int* __restrict__ cnt,
                                                const int* __restrict__ bsum,
                                                int* __restrict__ rowptr, int E) {
    __shared__ int sh[256];
    int i = blockIdx.x * 256 + threadIdx.x;
    int v = (i < NNODE) ? cnt[i] : 0;
    sh[threadIdx.x] = v;
    __syncthreads();
    for (int o = 1; o < 256; o <<= 1) {
        int x = (threadIdx.x >= o) ? sh[threadIdx.x - o] : 0;
        __syncthreads();
        sh[threadIdx.x] += x;
        __syncthreads();
    }
    if (i < NNODE) rowptr[i] = bsum[blockIdx.x] + sh[threadIdx.x] - v;  // exclusive
    if (i == NNODE - 1) rowptr[NNODE] = E;
}

// ---------------- scatter edges into CSR with pre-normalized weights ----------------
__global__ void scatter_edges(const int* __restrict__ row, const int* __restrict__ col,
                              const float* __restrict__ w, const float* __restrict__ dinv,
                              const int* __restrict__ rowptr, int* __restrict__ fill,
                              int* __restrict__ ecol, float* __restrict__ eval, int E) {
    int e = blockIdx.x * 256 + threadIdx.x;
    if (e < E) {
        int r = row[e], c = col[e];
        int pos = rowptr[r] + atomicAdd(&fill[r], 1);
        ecol[pos] = c;
        eval[pos] = dinv[r] * w[e] * dinv[c];
    }
}

// ---------------- fp32 -> bf16 elementwise ----------------
__global__ void f32_to_bf16(const float* __restrict__ in, short* __restrict__ out, int n4) {
    int i = blockIdx.x * 256 + threadIdx.x;
    if (i < n4) {
        float4 v = ((const float4*)in)[i];
        s16x4 s = { f2bf(v.x), f2bf(v.y), f2bf(v.z), f2bf(v.w) };
        *(s16x4*)(out + (size_t)i * 4) = s;
    }
}

// ---------------- transpose + convert: Wt[n][k] = bf16(W[k][n]) ----------------
__global__ __launch_bounds__(256) void transpose_bf16(const float* __restrict__ W,
                                                      short* __restrict__ Wt, int K, int N) {
    __shared__ float t[32][33];
    int kb = blockIdx.y * 32, nb = blockIdx.x * 32;
    int tx = threadIdx.x & 31, ty = threadIdx.x >> 5;     // 32 x 8
#pragma unroll
    for (int i = 0; i < 32; i += 8)
        if (kb + ty + i < K && nb + tx < N)
            t[ty + i][tx] = W[(size_t)(kb + ty + i) * N + nb + tx];
    __syncthreads();
#pragma unroll
    for (int i = 0; i < 32; i += 8)
        if (nb + ty + i < N && kb + tx < K)
            Wt[(size_t)(nb + ty + i) * K + kb + tx] = f2bf(t[tx][ty + i]);
}

// ---------------- CSR SpMM on bf16 rows, optional fused bias+L2norm+ReLU ----------------
template <int F, bool FUSE>
__global__ __launch_bounds__(256) void spmm_bf16(const int* __restrict__ rowptr,
                                                 const int* __restrict__ ecol,
                                                 const float* __restrict__ eval,
                                                 const float* __restrict__ dinv,
                                                 const short* __restrict__ h,
                                                 const float* __restrict__ bias,
                                                 short* __restrict__ out) {
    constexpr int NE = F / 64;               // 512->8, 256->4
    int lane = threadIdx.x & 63;
    int r = blockIdx.x * 4 + (threadIdx.x >> 6);
    if (r >= NNODE) return;
    float d = dinv[r];
    float dd = d * d;
    float acc[NE];
    {
        const short* p = h + (size_t)r * F + lane * NE;
        if constexpr (NE == 8) {
            s16x8 v = *(const s16x8*)p;
#pragma unroll
            for (int j = 0; j < 8; ++j) acc[j] = dd * bf2f(v[j]);
        } else {
            s16x4 v = *(const s16x4*)p;
#pragma unroll
            for (int j = 0; j < 4; ++j) acc[j] = dd * bf2f(v[j]);
        }
    }
    int e0 = rowptr[r], e1 = rowptr[r + 1];
    int e = e0;
    for (; e + 2 <= e1; e += 2) {
        int c0 = ecol[e], c1 = ecol[e + 1];
        float w0 = eval[e], w1 = eval[e + 1];
        const short* p0 = h + (size_t)c0 * F + lane * NE;
        const short* p1 = h + (size_t)c1 * F + lane * NE;
        if constexpr (NE == 8) {
            s16x8 v0 = *(const s16x8*)p0;
            s16x8 v1 = *(const s16x8*)p1;
#pragma unroll
            for (int j = 0; j < 8; ++j) acc[j] = fmaf(w0, bf2f(v0[j]), acc[j]);
#pragma unroll
            for (int j = 0; j < 8; ++j) acc[j] = fmaf(w1, bf2f(v1[j]), acc[j]);
        } else {
            s16x4 v0 = *(const s16x4*)p0;
            s16x4 v1 = *(const s16x4*)p1;
#pragma unroll
            for (int j = 0; j < 4; ++j) acc[j] = fmaf(w0, bf2f(v0[j]), acc[j]);
#pragma unroll
            for (int j = 0; j < 4; ++j) acc[j] = fmaf(w1, bf2f(v1[j]), acc[j]);
        }
    }
    if (e < e1) {
        int c = ecol[e];
        float nw = eval[e];
        const short* p = h + (size_t)c * F + lane * NE;
        if constexpr (NE == 8) {
            s16x8 v = *(const s16x8*)p;
#pragma unroll
            for (int j = 0; j < 8; ++j) acc[j] = fmaf(nw, bf2f(v[j]), acc[j]);
        } else {
            s16x4 v = *(const s16x4*)p;
#pragma unroll
            for (int j = 0; j < 4; ++j) acc[j] = fmaf(nw, bf2f(v[j]), acc[j]);
        }
    }
    short* o = out + (size_t)r * F + lane * NE;
    if (FUSE) {
        const float* bp = bias + lane * NE;
        float ss = 0.f;
#pragma unroll
        for (int j = 0; j < NE; ++j) { acc[j] += bp[j]; ss += acc[j] * acc[j]; }
#pragma unroll
        for (int off = 32; off; off >>= 1) ss += __shfl_xor(ss, off);
        float rinv = 1.0f / fmaxf(sqrtf(ss), 1e-12f);
#pragma unroll
        for (int j = 0; j < NE; ++j) acc[j] = fmaxf(acc[j] * rinv, 0.f);
    }
    if constexpr (NE == 8) {
        s16x8 s;
#pragma unroll
        for (int j = 0; j < 8; ++j) s[j] = f2bf(acc[j]);
        *(s16x8*)o = s;
    } else {
        s16x4 s;
#pragma unroll
        for (int j = 0; j < 4; ++j) s[j] = f2bf(acc[j]);
        *(s16x4*)o = s;
    }
}

// ---------------- stage one 64-wide K-tile (256 A-rows + 256 B-rows) into LDS ----------
// linear LDS dest (rule #21), T2 pre-swizzled global source column.
#define STAGE_TILE(buf_, kt_)                                                              \
  {                                                                                        \
    const int k0_ = (kt_) << 6;                                                            \
    _Pragma("unroll")                                                                      \
    for (int i_ = 0; i_ < 4; ++i_) {                                                       \
      int c_ = i_ * 8 + w;                                                                 \
      int tr_ = c_ * 8 + srow;                                                             \
      __builtin_amdgcn_global_load_lds(                                                    \
          (const __attribute__((address_space(1))) void*)(A + (size_t)(m0 + tr_) * K + k0_ + scol), \
          (__attribute__((address_space(3))) void*)(&sA[buf_][c_ * 512]), 16, 0, 0);       \
    }                                                                                      \
    _Pragma("unroll")                                                                      \
    for (int i_ = 0; i_ < 4; ++i_) {                                                       \
      int c_ = i_ * 8 + w;                                                                 \
      int tr_ = c_ * 8 + srow;                                                             \
      __builtin_amdgcn_global_load_lds(                                                    \
          (const __attribute__((address_space(1))) void*)(Bt + (size_t)(n0 + tr_) * K + k0_ + scol), \
          (__attribute__((address_space(3))) void*)(&sB[buf_][c_ * 512]), 16, 0, 0);       \
    }                                                                                      \
  }

// ---------------- bf16 MFMA GEMM: C[M][N] = A[118*256][K] * Bt[N][K]^T ------------------
// 256x256 tile (m201 geometry), BK=64, 512 threads = 8 waves as 2M x 4N; per-wave output
// 128x64 -> 24 ds_read_b128 per 64 MFMA per K-step (2.67 MFMA/read vs 2.0 at 64x64/wave).
// Double-buffered LDS 128KB; 2-phase: STAGE(next) -> compute(cur) -> one __syncthreads
// (its vmcnt/lgkm drain readies next buf and retires cur reads). T2 swizzle; m204
// bijective XCD swizzle; setprio(1) around MFMA cluster (T5).
// EPI: 0 plain(+bias) | 1 bias+ReLU+row-SS atomics | 2 row-scale by ssbuf | 3 dual split
template <typename OutT, bool ADD_BIAS, int EPI>
__global__ __launch_bounds__(512) void gemm_bf16(const short* __restrict__ A,
                                                 const short* __restrict__ Bt,
                                                 const float* __restrict__ bias,
                                                 const float* __restrict__ bias2,
                                                 OutT* __restrict__ C,
                                                 float* __restrict__ C2,
                                                 float* __restrict__ ssbuf,
                                                 int M, int N, int K) {
    __shared__ short sA[2][256 * 64];
    __shared__ short sB[2][256 * 64];
    const int tid = threadIdx.x;
    const int lane = tid & 63;
    const int w = tid >> 6;                 // wave 0..7
    const int wm = w >> 2, wn = w & 3;      // 2M x 4N; per-wave 128 rows x 64 cols

    // ---- m204 bijective XCD swizzle over nwg blocks ----
    const int nwg = gridDim.x;
    const int orig = blockIdx.x;
    const int q = nwg >> 3, rr = nwg & 7;
    const int xcd = orig & 7;
    const int base = (xcd < rr) ? xcd * (q + 1) : rr * (q + 1) + (xcd - rr) * q;
    const int wgid = base + (orig >> 3);
    const int nx = N >> 8;                  // N-blocks of 256
    const int lg = __builtin_ctz(nx);
    const int pid = wgid >> lg;             // M-panel (256 rows)
    const int cblk = wgid & (nx - 1);
    const int m0 = pid << 8;
    const int n0 = cblk << 8;

    const int srow = lane >> 3;             // 0..7
    const int scol = ((lane & 7) ^ srow) * 8;   // T2 pre-swizzled source col

    f32x4 acc[8][4] = {};

    const int lrow = lane & 15;
    const int jhi = lane >> 4;              // 0..3

    const int nkt = K >> 6;
    int cur = 0;
    STAGE_TILE(0, 0);
    __syncthreads();                        // drains vmcnt(0): buf0 ready

    for (int kt = 0; kt < nkt; ++kt) {
        if (kt + 1 < nkt) STAGE_TILE(cur ^ 1, kt + 1);   // overlaps compute below

        s16x8 bfr[4][2];
#pragma unroll
        for (int fn = 0; fn < 4; ++fn) {
            int lr = wn * 64 + fn * 16 + lrow;
            const short* bptr = &sB[cur][lr * 64];
            int sl0 = jhi ^ (lr & 7);
            bfr[fn][0] = *(const s16x8*)&bptr[sl0 << 3];
            bfr[fn][1] = *(const s16x8*)&bptr[(sl0 ^ 4) << 3];
        }
        __builtin_amdgcn_s_setprio(1);
#pragma unroll
        for (int fm = 0; fm < 8; ++fm) {
            int lr = wm * 128 + fm * 16 + lrow;
            const short* aptr = &sA[cur][lr * 64];
            int sl0 = jhi ^ (lr & 7);
            s16x8 a0 = *(const s16x8*)&aptr[sl0 << 3];
            s16x8 a1 = *(const s16x8*)&aptr[(sl0 ^ 4) << 3];
#pragma unroll
            for (int fn = 0; fn < 4; ++fn) {
                acc[fm][fn] = __builtin_amdgcn_mfma_f32_16x16x32_bf16(a0, bfr[fn][0], acc[fm][fn], 0, 0, 0);
                acc[fm][fn] = __builtin_amdgcn_mfma_f32_16x16x32_bf16(a1, bfr[fn][1], acc[fm][fn], 0, 0, 0);
            }
        }
        __builtin_amdgcn_s_setprio(0);
        __syncthreads();                    // retires cur reads + drains stage of cur^1
        cur ^= 1;
    }

    const int crow = (lane >> 4) * 4;
    const int ccol = lane & 15;

    if constexpr (EPI == 1) {
        float ssl[8][4] = {};
#pragma unroll
        for (int fm = 0; fm < 8; ++fm) {
#pragma unroll
            for (int fn = 0; fn < 4; ++fn) {
                int n = n0 + wn * 64 + fn * 16 + ccol;
                float b = bias[n];
#pragma unroll
                for (int r = 0; r < 4; ++r) {
                    float o = acc[fm][fn][r] + b;
                    ssl[fm][r] += o * o;
                    int m = m0 + wm * 128 + fm * 16 + crow + r;
                    if (m < M) C[(size_t)m * N + n] = (OutT)f2bf(fmaxf(o, 0.f));
                }
            }
        }
#pragma unroll
        for (int fm = 0; fm < 8; ++fm)
#pragma unroll
            for (int r = 0; r < 4; ++r) {
                float v = ssl[fm][r];
                v += __shfl_xor(v, 1); v += __shfl_xor(v, 2);
                v += __shfl_xor(v, 4); v += __shfl_xor(v, 8);
                int m = m0 + wm * 128 + fm * 16 + crow + r;
                if (ccol == 0 && m < M) atomicAdd(&ssbuf[m], v);
            }
    } else if constexpr (EPI == 2) {
#pragma unroll
        for (int fm = 0; fm < 8; ++fm) {
#pragma unroll
            for (int fn = 0; fn < 4; ++fn) {
                int n = n0 + wn * 64 + fn * 16 + ccol;
#pragma unroll
                for (int r = 0; r < 4; ++r) {
                    int m = m0 + wm * 128 + fm * 16 + crow + r;
                    if (m < M) {
                        float sc = ssbuf[m];
                        C[(size_t)m * N + n] = (OutT)f2bf(acc[fm][fn][r] * sc);
                    }
                }
            }
        }
    } else if constexpr (EPI == 3) {
        const int half = N >> 1;
#pragma unroll
        for (int fm = 0; fm < 8; ++fm) {
#pragma unroll
            for (int fn = 0; fn < 4; ++fn) {
                int n = n0 + wn * 64 + fn * 16 + ccol;
                bool hi = n >= half;
                float b = hi ? bias2[n - half] : bias[n];
                float* Cp = hi ? C2 : (float*)C;
                int nc = hi ? (n - half) : n;
#pragma unroll
                for (int r = 0; r < 4; ++r) {
                    int m = m0 + wm * 128 + fm * 16 + crow + r;
                    if (m < M) Cp[(size_t)m * half + nc] = acc[fm][fn][r] + b;
                }
            }
        }
    } else {
#pragma unroll
        for (int fm = 0; fm < 8; ++fm) {
#pragma unroll
            for (int fn = 0; fn < 4; ++fn) {
                int n = n0 + wn * 64 + fn * 16 + ccol;
                float b = ADD_BIAS ? bias[n] : 0.f;
#pragma unroll
                for (int r = 0; r < 4; ++r) {
                    int m = m0 + wm * 128 + fm * 16 + crow + r;
                    if (m < M) {
                        float o = acc[fm][fn][r] + b;
                        if constexpr (sizeof(OutT) == 2) C[(size_t)m * N + n] = (OutT)f2bf(o);
                        else                             C[(size_t)m * N + n] = o;
                    }
                }
            }
        }
    }
}

// ---------------- pooling stage 1: 938 blocks x 16 row-pairs ----------------
__global__ __launch_bounds__(256) void pool_partial(const float* __restrict__ mu,
                                                    const float* __restrict__ lv,
                                                    const uint32_t* __restrict__ beta_p,
                                                    float* __restrict__ pmax,
                                                    float* __restrict__ psum) {
    uint32_t bb = beta_p[0];
    float beta = (bb & 0x7F800000u) ? __uint_as_float(bb) : (float)(int)bb;
    int b = blockIdx.x;
    int r0 = b * PP_ROWS;
    int r1 = min(r0 + PP_ROWS, HALF_ROWS);
    int c = threadIdx.x * 2;
    float m0 = -INFINITY, m1 = -INFINITY, s0 = 0.f, s1 = 0.f;
    for (int r = r0; r < r1; ++r) {
        size_t ia = (size_t)r * HDIM + c;
        size_t ib = (size_t)(r + HALF_ROWS) * HDIM + c;
        float2 mua = *(const float2*)&mu[ia];
        float2 lva = *(const float2*)&lv[ia];
        float2 mub = *(const float2*)&mu[ib];
        float2 lvb = *(const float2*)&lv[ib];
        uint32_t idx0 = (uint32_t)r * 512u + (uint32_t)c;
        uint32_t xa0 = idx0,     ya0 = idx0 + HALF_ELEMS;
        uint32_t xa1 = idx0 + 1, ya1 = idx0 + 1 + HALF_ELEMS;
        threefry2x32(0u, 42u, xa0, ya0);
        threefry2x32(0u, 42u, xa1, ya1);
        float za0 = mua.x + 0.01f * jax_normal(xa0) * __expf(0.5f * beta * lva.x);
        float zb0 = mub.x + 0.01f * jax_normal(ya0) * __expf(0.5f * beta * lvb.x);
        float za1 = mua.y + 0.01f * jax_normal(xa1) * __expf(0.5f * beta * lva.y);
        float zb1 = mub.y + 0.01f * jax_normal(ya1) * __expf(0.5f * beta * lvb.y);
        m0 = fmaxf(m0, fmaxf(za0, zb0)); s0 += za0 + zb0;
        m1 = fmaxf(m1, fmaxf(za1, zb1)); s1 += za1 + zb1;
    }
    pmax[(size_t)b * HDIM + c]     = m0;
    pmax[(size_t)b * HDIM + c + 1] = m1;
    psum[(size_t)b * HDIM + c]     = s0;
    psum[(size_t)b * HDIM + c + 1] = s1;
}

// ---------------- pooling stage 2: 938 -> 64 partials ----------------
__global__ __launch_bounds__(256) void pool_mid(const float* __restrict__ pmax,
                                                const float* __restrict__ psum,
                                                float* __restrict__ pmax2,
                                                float* __restrict__ psum2) {
    int g = blockIdx.x;
    int b0 = g * 15;
    int b1 = min(b0 + 15, PP_BLOCKS);
#pragma unroll
    for (int pass = 0; pass < 2; ++pass) {
        int c = threadIdx.x + pass * 256;
        float m = -INFINITY, s = 0.f;
        for (int b = b0; b < b1; ++b) {
            m = fmaxf(m, pmax[(size_t)b * HDIM + c]);
            s += psum[(size_t)b * HDIM + c];
        }
        pmax2[(size_t)g * HDIM + c] = m;
        psum2[(size_t)g * HDIM + c] = s;
    }
}

// ---------------- pooling stage 3: 64 -> pooled[1024] ----------------
__global__ void pool_final(const float* __restrict__ pmax2, const float* __restrict__ psum2,
                           float* __restrict__ pooled) {
    int c = blockIdx.x * 256 + threadIdx.x;
    if (c < HDIM) {
        float m = -INFINITY, s = 0.f;
#pragma unroll
        for (int b = 0; b < PM_BLOCKS; ++b) {
            m = fmaxf(m, pmax2[(size_t)b * HDIM + c]);
            s += psum2[(size_t)b * HDIM + c];
        }
        pooled[c] = m;
        pooled[HDIM + c] = s / 30000.0f;
    }
}

// ---------------- decoder: split-K partial + finalize ----------------
__global__ __launch_bounds__(256) void dense_partial(const float* __restrict__ in,
                                                     const float* __restrict__ W,
                                                     float* __restrict__ part) {
    int by = blockIdx.y;                           // k-slice 0..7 (128 rows each)
    int j = blockIdx.x * 256 + threadIdx.x;        // 0..1023
    __shared__ float sin_[128];
    if (threadIdx.x < 128) sin_[threadIdx.x] = in[by * 128 + threadIdx.x];
    __syncthreads();
    float acc = 0.f;
#pragma unroll 8
    for (int i = 0; i < 128; ++i)
        acc = fmaf(sin_[i], W[(size_t)(by * 128 + i) * 1024 + j], acc);
    part[(size_t)by * 1024 + j] = acc;
}

__global__ void dense_final(const float* __restrict__ part, const float* __restrict__ bias,
                            float* __restrict__ out, int act) {
    int j = blockIdx.x * 256 + threadIdx.x;
    float acc = bias[j];
#pragma unroll
    for (int s = 0; s < 8; ++s) acc += part[(size_t)s * 1024 + j];
    out[j] = act ? (1.0f / (1.0f + __expf(-acc))) : fmaxf(acc, 0.f);
}

// ---------------- launch ----------------
extern "C" void kernel_launch(void* const* d_in, const int* in_sizes, int n_in,
                              void* d_out, int out_size, void* d_ws, size_t ws_size,
                              hipStream_t stream) {
    const float* x   = (const float*)d_in[0];
    const int*   ei  = (const int*)d_in[1];
    const float* ew  = (const float*)d_in[2];
    const uint32_t* beta = (const uint32_t*)d_in[3];
    const float* W1  = (const float*)d_in[4];
    const float* b1  = (const float*)d_in[5];
    const float* W2  = (const float*)d_in[6];
    const float* b2  = (const float*)d_in[7];
    const float* W3  = (const float*)d_in[8];
    const float* b3  = (const float*)d_in[9];
    const float* Wmu = (const float*)d_in[10];
    const float* bmu = (const float*)d_in[11];
    const float* Wlv = (const float*)d_in[12];
    const float* blv = (const float*)d_in[13];
    const float* Wd1 = (const float*)d_in[14];
    const float* bd1 = (const float*)d_in[15];
    const float* Wd2 = (const float*)d_in[16];
    const float* bd2 = (const float*)d_in[17];

    const int E = in_sizes[2];            // 300000
    const int M = NNODE;

    float* out    = (float*)d_out;
    float* mu_out = out + 1024;                           // [30000,512]
    float* lv_out = out + 1024 + (size_t)M * HDIM;        // [30000,512]

    // ---------------- workspace layout (bytes); no trailing backslashes in comments ----
    char* Wp = (char*)d_ws;
    short* slotA  = (short*)(Wp);                         // 61,603,840 B
    short* slotB  = (short*)(Wp + 61603840);              // 61,603,840 B
    short* xb     = (short*)(Wp + 123207680);             // 30,720,000 B
    short* W1t    = (short*)(Wp + 154009600);             // 1024x512
    short* W2t    = (short*)(Wp + 155058176);             // 512x1024
    short* W3t    = (short*)(Wp + 156106752);             // 256x512
    short* Wmut   = (short*)(Wp + 156368896);             // 512x256 (Wlvt MUST follow)
    short* Wlvt   = (short*)(Wp + 156631040);             // 512x256 = Wmut + 262144 B
    float* deg    = (float*)(Wp + 156893184);             // 120,000 B (memset group start)
    float* dinv   = (float*)(Wp + 157013184);             // 120,000 B
    int*   cnt    = (int*)  (Wp + 157133184);             // 120,000 B
    int*   fill   = (int*)  (Wp + 157253184);             // 120,000 B
    float* ssbuf  = (float*)(Wp + 157373184);             // 120,000 B (memset group end)
    int*   rowptr = (int*)  (Wp + 157493184);             // 120,004 B
    int*   ecol   = (int*)  (Wp + 157613188);             // 1,200,000 B
    float* eval   = (float*)(Wp + 158813188);             // 1,200,000 B
    float* pmax   = (float*)(Wp + 160013188);             // 1,921,024 B
    float* psum   = (float*)(Wp + 161934212);             // 1,921,024 B
    float* pmax2  = (float*)(Wp + 163855236);             // 131,072 B
    float* psum2  = (float*)(Wp + 163986308);             // 131,072 B
    float* pooled = (float*)(Wp + 164117380);             // 4,096 B
    float* hdec   = (float*)(Wp + 164121476);             // 4,096 B
    float* dpart  = (float*)(Wp + 164125572);             // 32,768 B
    int*   bsum   = (int*)pmax;                           // scan scratch; pmax unused until pooling

    const int* row = ei;
    const int* col = ei + E;

    // 1) one memset for deg|dinv|cnt|fill|ssbuf
    hipMemsetAsync(deg, 0, 600000, stream);

    deg_cnt_kernel<<<(E + 255) / 256, 256, 0, stream>>>(row, ew, deg, cnt, E);
    dinv_kernel<<<(M + 255) / 256, 256, 0, stream>>>(deg, dinv, M);
    rp_blocksum<<<NSCAN, 256, 0, stream>>>(cnt, bsum);
    rp_scan<<<1, 128, 0, stream>>>(bsum, NSCAN);
    rp_write<<<NSCAN, 256, 0, stream>>>(cnt, bsum, rowptr, E);
    scatter_edges<<<(E + 255) / 256, 256, 0, stream>>>(row, col, ew, dinv, rowptr, fill,
                                                       ecol, eval, E);

    // 2) conversions: x -> bf16, weights -> transposed bf16 [N][K]
    f32_to_bf16<<<(M * FIN / 4 + 255) / 256, 256, 0, stream>>>(x, xb, M * FIN / 4);
    {
        dim3 b(256);
        transpose_bf16<<<dim3(H1DIM / 32, FIN / 32),   b, 0, stream>>>(W1,  W1t,  FIN,   H1DIM);
        transpose_bf16<<<dim3(H2DIM / 32, H1DIM / 32), b, 0, stream>>>(W2,  W2t,  H1DIM, H2DIM);
        transpose_bf16<<<dim3(H3DIM / 32, H2DIM / 32), b, 0, stream>>>(W3,  W3t,  H2DIM, H3DIM);
        transpose_bf16<<<dim3(HDIM / 32,  H3DIM / 32), b, 0, stream>>>(Wmu, Wmut, H3DIM, HDIM);
        transpose_bf16<<<dim3(HDIM / 32,  H3DIM / 32), b, 0, stream>>>(Wlv, Wlvt, H3DIM, HDIM);
    }

    const int SPMM_GRID = (M + 3) / 4;

    // 3) layer 1: AXb = A_hat@xb (slotA); relu_h1 + row-ss = AXb@W1t+b1 (slotB, EPI1)
    spmm_bf16<512, false><<<SPMM_GRID, 256, 0, stream>>>(rowptr, ecol, eval, dinv, xb,
                                                         nullptr, slotA);
    gemm_bf16<short, true, 1><<<(H1DIM / 256) * NPANEL, 512, 0, stream>>>(
        slotA, W1t, b1, nullptr, slotB, nullptr, ssbuf, M, H1DIM, FIN);
    rsqrt_clamp_kernel<<<(M + 255) / 256, 256, 0, stream>>>(ssbuf, M);

    // 4) layer 2: h2 = (relu_h1 @ W2t) * rinv[row] (slotA, EPI2); out2 = fused spmm (slotB)
    gemm_bf16<short, false, 2><<<(H2DIM / 256) * NPANEL, 512, 0, stream>>>(
        slotB, W2t, nullptr, nullptr, slotA, nullptr, ssbuf, M, H2DIM, H1DIM);
    spmm_bf16<512, true><<<SPMM_GRID, 256, 0, stream>>>(rowptr, ecol, eval, dinv, slotA,
                                                        b2, slotB);

    // 5) layer 3: h3 = out2@W3t (slotA); out3 = fused spmm (slotB)
    gemm_bf16<short, false, 0><<<(H3DIM / 256) * NPANEL, 512, 0, stream>>>(
        slotB, W3t, nullptr, nullptr, slotA, nullptr, nullptr, M, H3DIM, H2DIM);
    spmm_bf16<256, true><<<SPMM_GRID, 256, 0, stream>>>(rowptr, ecol, eval, dinv, slotA,
                                                        b3, slotB);

    // 6) mu / logvar in ONE GEMM (Bt = [Wmut;Wlvt] contiguous, N=1024, split epilogue)
    gemm_bf16<float, true, 3><<<((2 * HDIM) / 256) * NPANEL, 512, 0, stream>>>(
        slotB, Wmut, bmu, blv, mu_out, lv_out, nullptr, M, 2 * HDIM, H3DIM);

    // 7) pooling with JAX-exact reparameterization noise (3-stage tree)
    pool_partial<<<PP_BLOCKS, 256, 0, stream>>>(mu_out, lv_out, beta, pmax, psum);
    pool_mid<<<PM_BLOCKS, 256, 0, stream>>>(pmax, psum, pmax2, psum2);
    pool_final<<<2, 256, 0, stream>>>(pmax2, psum2, pooled);

    // 8) decoder (split-K)
    dense_partial<<<dim3(4, 8), 256, 0, stream>>>(pooled, Wd1, dpart);
    dense_final<<<4, 256, 0, stream>>>(dpart, bd1, hdec, 0);
    dense_partial<<<dim3(4, 8), 256, 0, stream>>>(hdec, Wd2, dpart);
    dense_final<<<4, 256, 0, stream>>>(dpart, bd2, out, 1);
}

// Round 11
// 483.195 us; speedup vs baseline: 1.0186x; 1.0186x over previous
//
#include <hip/hip_runtime.h>
#include <cstdint>
#include <cstddef>

// ---------------- problem constants ----------------
#define NNODE      30000
#define FIN        512
#define H1DIM      1024
#define H2DIM      512
#define H3DIM      256
#define HDIM       512          // mu/logvar width
#define HALF_ROWS  15000
#define HALF_ELEMS 7680000u     // 15000*512 (threefry pair offset)
#define PP_ROWS    8
#define PP_BLOCKS  1875         // 15000/8
#define PM_BLOCKS  63           // mid-reduce blocks (30 pp-blocks each)
#define NPANEL     118          // ceil(30000/256) M-panels (BM=256)
#define NSCAN      118          // ceil(30000/256) scan blocks

typedef __attribute__((ext_vector_type(8))) short s16x8;
typedef __attribute__((ext_vector_type(4))) short s16x4;
typedef __attribute__((ext_vector_type(4))) float f32x4;

// bf16 <-> f32 (RNE, matches JAX/torch)
__device__ __forceinline__ short f2bf(float f) {
    uint32_t u = __float_as_uint(f);
    uint32_t r = (u + 0x7FFFu + ((u >> 16) & 1u)) >> 16;
    return (short)r;
}
__device__ __forceinline__ float bf2f(short s) {
    return __uint_as_float(((uint32_t)(uint16_t)s) << 16);
}

// ---------------- threefry2x32 (JAX-exact) ----------------
__device__ __forceinline__ void threefry2x32(uint32_t k0, uint32_t k1,
                                             uint32_t& x0, uint32_t& x1) {
    uint32_t ks0 = k0, ks1 = k1, ks2 = k0 ^ k1 ^ 0x1BD11BDAu;
    const uint32_t R0[4] = {13u, 15u, 26u, 6u};
    const uint32_t R1[4] = {17u, 29u, 16u, 24u};
    x0 += ks0; x1 += ks1;
#pragma unroll
    for (int g = 0; g < 5; ++g) {
        const uint32_t* R = (g & 1) ? R1 : R0;
#pragma unroll
        for (int r = 0; r < 4; ++r) {
            x0 += x1;
            x1 = (x1 << R[r]) | (x1 >> (32u - R[r]));
            x1 ^= x0;
        }
        uint32_t ks_a = (g % 3 == 0) ? ks1 : (g % 3 == 1 ? ks2 : ks0);
        uint32_t ks_b = (g % 3 == 0) ? ks2 : (g % 3 == 1 ? ks0 : ks1);
        x0 += ks_a;
        x1 += ks_b + (uint32_t)(g + 1);
    }
}

__device__ __forceinline__ float jax_normal(uint32_t bits) {
    uint32_t fb = (bits >> 9) | 0x3F800000u;
    float f = __uint_as_float(fb) - 1.0f;
    const float lo = -0.99999994f;
    float u = fmaf(f, 2.0f, lo);
    u = fmaxf(u, lo);
    return 1.41421356237f * erfinvf(u);
}

// ---------------- degree + count ----------------
__global__ void deg_cnt_kernel(const int* __restrict__ row, const float* __restrict__ w,
                               float* __restrict__ deg, int* __restrict__ cnt, int E) {
    int e = blockIdx.x * 256 + threadIdx.x;
    if (e < E) {
        int r = row[e];
        atomicAdd(&deg[r], w[e]);
        atomicAdd(&cnt[r], 1);
    }
}

__global__ void dinv_kernel(const float* __restrict__ deg, float* __restrict__ dinv, int n) {
    int i = blockIdx.x * 256 + threadIdx.x;
    if (i < n) dinv[i] = rsqrtf(deg[i] + 1.0f);
}

// ---------------- parallel rowptr build: blocksum -> scan -> write ----------------
__global__ __launch_bounds__(256) void rp_blocksum(const int* __restrict__ cnt,
                                                   int* __restrict__ bsum) {
    __shared__ int sh[256];
    int i = blockIdx.x * 256 + threadIdx.x;
    sh[threadIdx.x] = (i < NNODE) ? cnt[i] : 0;
    __syncthreads();
    for (int o = 128; o; o >>= 1) {
        if (threadIdx.x < o) sh[threadIdx.x] += sh[threadIdx.x + o];
        __syncthreads();
    }
    if (threadIdx.x == 0) bsum[blockIdx.x] = sh[0];
}

__global__ __launch_bounds__(128) void rp_scan(int* __restrict__ bsum, int nb) {
    __shared__ int sh[128];
    int t = threadIdx.x;
    sh[t] = (t < nb) ? bsum[t] : 0;
    __syncthreads();
    for (int o = 1; o < 128; o <<= 1) {
        int v = (t >= o) ? sh[t - o] : 0;
        __syncthreads();
        sh[t] += v;
        __syncthreads();
    }
    if (t < nb) bsum[t] = (t == 0) ? 0 : sh[t - 1];   // exclusive
}

__global__ __launch_bounds__(256) void rp_write(const int* __restrict__ cnt,
                                                const int* __restrict__ bsum,
                                                int* __restrict__ rowptr, int E) {
    __shared__ int sh[256];
    int i = blockIdx.x * 256 + threadIdx.x;
    int v = (i < NNODE) ? cnt[i] : 0;
    sh[threadIdx.x] = v;
    __syncthreads();
    for (int o = 1; o < 256; o <<= 1) {
        int x = (threadIdx.x >= o) ? sh[threadIdx.x - o] : 0;
        __syncthreads();
        sh[threadIdx.x] += x;
        __syncthreads();
    }
    if (i < NNODE) rowptr[i] = bsum[blockIdx.x] + sh[threadIdx.x] - v;  // exclusive
    if (i == NNODE - 1) rowptr[NNODE] = E;
}

// ---------------- scatter edges into CSR with pre-normalized weights ----------------
__global__ void scatter_edges(const int* __restrict__ row, const int* __restrict__ col,
                              const float* __restrict__ w, const float* __restrict__ dinv,
                              const int* __restrict__ rowptr, int* __restrict__ fill,
                              int* __restrict__ ecol, float* __restrict__ eval, int E) {
    int e = blockIdx.x * 256 + threadIdx.x;
    if (e < E) {
        int r = row[e], c = col[e];
        int pos = rowptr[r] + atomicAdd(&fill[r], 1);
        ecol[pos] = c;
        eval[pos] = dinv[r] * w[e] * dinv[c];
    }
}

// ---------------- fp32 -> bf16 elementwise ----------------
__global__ void f32_to_bf16(const float* __restrict__ in, short* __restrict__ out, int n4) {
    int i = blockIdx.x * 256 + threadIdx.x;
    if (i < n4) {
        float4 v = ((const float4*)in)[i];
        s16x4 s = { f2bf(v.x), f2bf(v.y), f2bf(v.z), f2bf(v.w) };
        *(s16x4*)(out + (size_t)i * 4) = s;
    }
}

// ---------------- transpose + convert: Wt[n][k] = bf16(W[k][n]) ----------------
__global__ __launch_bounds__(256) void transpose_bf16(const float* __restrict__ W,
                                                      short* __restrict__ Wt, int K, int N) {
    __shared__ float t[32][33];
    int kb = blockIdx.y * 32, nb = blockIdx.x * 32;
    int tx = threadIdx.x & 31, ty = threadIdx.x >> 5;     // 32 x 8
#pragma unroll
    for (int i = 0; i < 32; i += 8)
        if (kb + ty + i < K && nb + tx < N)
            t[ty + i][tx] = W[(size_t)(kb + ty + i) * N + nb + tx];
    __syncthreads();
#pragma unroll
    for (int i = 0; i < 32; i += 8)
        if (nb + ty + i < N && kb + tx < K)
            Wt[(size_t)(nb + ty + i) * K + kb + tx] = f2bf(t[tx][ty + i]);
}

// ---------------- CSR SpMM on bf16 rows; 4x-unrolled edge loop (4 gathers in flight) ----
template <int F, bool FUSE>
__global__ __launch_bounds__(256) void spmm_bf16(const int* __restrict__ rowptr,
                                                 const int* __restrict__ ecol,
                                                 const float* __restrict__ eval,
                                                 const float* __restrict__ dinv,
                                                 const short* __restrict__ h,
                                                 const float* __restrict__ bias,
                                                 short* __restrict__ out) {
    constexpr int NE = F / 64;               // 512->8, 256->4
    int lane = threadIdx.x & 63;
    int r = blockIdx.x * 4 + (threadIdx.x >> 6);
    if (r >= NNODE) return;
    float d = dinv[r];
    float dd = d * d;
    float acc[NE];
    {
        const short* p = h + (size_t)r * F + lane * NE;
        if constexpr (NE == 8) {
            s16x8 v = *(const s16x8*)p;
#pragma unroll
            for (int j = 0; j < 8; ++j) acc[j] = dd * bf2f(v[j]);
        } else {
            s16x4 v = *(const s16x4*)p;
#pragma unroll
            for (int j = 0; j < 4; ++j) acc[j] = dd * bf2f(v[j]);
        }
    }
    int e0 = rowptr[r], e1 = rowptr[r + 1];
    int e = e0;
    for (; e + 4 <= e1; e += 4) {
        int   c0 = ecol[e],     c1 = ecol[e + 1], c2 = ecol[e + 2], c3 = ecol[e + 3];
        float w0 = eval[e],     w1 = eval[e + 1], w2 = eval[e + 2], w3 = eval[e + 3];
        const short* p0 = h + (size_t)c0 * F + lane * NE;
        const short* p1 = h + (size_t)c1 * F + lane * NE;
        const short* p2 = h + (size_t)c2 * F + lane * NE;
        const short* p3 = h + (size_t)c3 * F + lane * NE;
        if constexpr (NE == 8) {
            s16x8 v0 = *(const s16x8*)p0;
            s16x8 v1 = *(const s16x8*)p1;
            s16x8 v2 = *(const s16x8*)p2;
            s16x8 v3 = *(const s16x8*)p3;
#pragma unroll
            for (int j = 0; j < 8; ++j) acc[j] = fmaf(w0, bf2f(v0[j]), acc[j]);
#pragma unroll
            for (int j = 0; j < 8; ++j) acc[j] = fmaf(w1, bf2f(v1[j]), acc[j]);
#pragma unroll
            for (int j = 0; j < 8; ++j) acc[j] = fmaf(w2, bf2f(v2[j]), acc[j]);
#pragma unroll
            for (int j = 0; j < 8; ++j) acc[j] = fmaf(w3, bf2f(v3[j]), acc[j]);
        } else {
            s16x4 v0 = *(const s16x4*)p0;
            s16x4 v1 = *(const s16x4*)p1;
            s16x4 v2 = *(const s16x4*)p2;
            s16x4 v3 = *(const s16x4*)p3;
#pragma unroll
            for (int j = 0; j < 4; ++j) acc[j] = fmaf(w0, bf2f(v0[j]), acc[j]);
#pragma unroll
            for (int j = 0; j < 4; ++j) acc[j] = fmaf(w1, bf2f(v1[j]), acc[j]);
#pragma unroll
            for (int j = 0; j < 4; ++j) acc[j] = fmaf(w2, bf2f(v2[j]), acc[j]);
#pragma unroll
            for (int j = 0; j < 4; ++j) acc[j] = fmaf(w3, bf2f(v3[j]), acc[j]);
        }
    }
    for (; e < e1; ++e) {
        int c = ecol[e];
        float nw = eval[e];
        const short* p = h + (size_t)c * F + lane * NE;
        if constexpr (NE == 8) {
            s16x8 v = *(const s16x8*)p;
#pragma unroll
            for (int j = 0; j < 8; ++j) acc[j] = fmaf(nw, bf2f(v[j]), acc[j]);
        } else {
            s16x4 v = *(const s16x4*)p;
#pragma unroll
            for (int j = 0; j < 4; ++j) acc[j] = fmaf(nw, bf2f(v[j]), acc[j]);
        }
    }
    short* o = out + (size_t)r * F + lane * NE;
    if (FUSE) {
        const float* bp = bias + lane * NE;
        float ss = 0.f;
#pragma unroll
        for (int j = 0; j < NE; ++j) { acc[j] += bp[j]; ss += acc[j] * acc[j]; }
#pragma unroll
        for (int off = 32; off; off >>= 1) ss += __shfl_xor(ss, off);
        float rinv = 1.0f / fmaxf(sqrtf(ss), 1e-12f);
#pragma unroll
        for (int j = 0; j < NE; ++j) acc[j] = fmaxf(acc[j] * rinv, 0.f);
    }
    if constexpr (NE == 8) {
        s16x8 s;
#pragma unroll
        for (int j = 0; j < 8; ++j) s[j] = f2bf(acc[j]);
        *(s16x8*)o = s;
    } else {
        s16x4 s;
#pragma unroll
        for (int j = 0; j < 4; ++j) s[j] = f2bf(acc[j]);
        *(s16x4*)o = s;
    }
}

// ---------------- stage one 64-wide K-tile (256 A-rows + 256 B-rows) into LDS ----------
// linear LDS dest (rule #21), T2 pre-swizzled global source column.
#define STAGE_TILE(buf_, kt_)                                                              \
  {                                                                                        \
    const int k0_ = (kt_) << 6;                                                            \
    _Pragma("unroll")                                                                      \
    for (int i_ = 0; i_ < 4; ++i_) {                                                       \
      int c_ = i_ * 8 + w;                                                                 \
      int tr_ = c_ * 8 + srow;                                                             \
      __builtin_amdgcn_global_load_lds(                                                    \
          (const __attribute__((address_space(1))) void*)(A + (size_t)(m0 + tr_) * K + k0_ + scol), \
          (__attribute__((address_space(3))) void*)(&sA[buf_][c_ * 512]), 16, 0, 0);       \
    }                                                                                      \
    _Pragma("unroll")                                                                      \
    for (int i_ = 0; i_ < 4; ++i_) {                                                       \
      int c_ = i_ * 8 + w;                                                                 \
      int tr_ = c_ * 8 + srow;                                                             \
      __builtin_amdgcn_global_load_lds(                                                    \
          (const __attribute__((address_space(1))) void*)(Bt + (size_t)(n0 + tr_) * K + k0_ + scol), \
          (__attribute__((address_space(3))) void*)(&sB[buf_][c_ * 512]), 16, 0, 0);       \
    }                                                                                      \
  }

// ---------------- bf16 MFMA GEMM: C[M][N] = A[118*256][K] * Bt[N][K]^T ------------------
// 256x256 tile, BK=64, 512 threads = 8 waves (2M x 4N), per-wave 128x64 output.
// Double-buffered LDS 128KB; 2-phase STAGE(next)->compute(cur)->one barrier. T2 swizzle;
// m204 bijective XCD swizzle; setprio around MFMA cluster.
// EPI: 0 plain(+bias) | 1 bias+ReLU+row-SS atomics | 2 row-scale rinv(ssbuf) | 3 dual split
template <typename OutT, bool ADD_BIAS, int EPI>
__global__ __launch_bounds__(512) void gemm_bf16(const short* __restrict__ A,
                                                 const short* __restrict__ Bt,
                                                 const float* __restrict__ bias,
                                                 const float* __restrict__ bias2,
                                                 OutT* __restrict__ C,
                                                 float* __restrict__ C2,
                                                 float* __restrict__ ssbuf,
                                                 int M, int N, int K) {
    __shared__ short sA[2][256 * 64];
    __shared__ short sB[2][256 * 64];
    const int tid = threadIdx.x;
    const int lane = tid & 63;
    const int w = tid >> 6;                 // wave 0..7
    const int wm = w >> 2, wn = w & 3;      // 2M x 4N; per-wave 128 rows x 64 cols

    // ---- m204 bijective XCD swizzle over nwg blocks ----
    const int nwg = gridDim.x;
    const int orig = blockIdx.x;
    const int q = nwg >> 3, rr = nwg & 7;
    const int xcd = orig & 7;
    const int base = (xcd < rr) ? xcd * (q + 1) : rr * (q + 1) + (xcd - rr) * q;
    const int wgid = base + (orig >> 3);
    const int nx = N >> 8;                  // N-blocks of 256
    const int lg = __builtin_ctz(nx);
    const int pid = wgid >> lg;             // M-panel (256 rows)
    const int cblk = wgid & (nx - 1);
    const int m0 = pid << 8;
    const int n0 = cblk << 8;

    const int srow = lane >> 3;             // 0..7
    const int scol = ((lane & 7) ^ srow) * 8;   // T2 pre-swizzled source col

    f32x4 acc[8][4] = {};

    const int lrow = lane & 15;
    const int jhi = lane >> 4;              // 0..3

    const int nkt = K >> 6;
    int cur = 0;
    STAGE_TILE(0, 0);
    __syncthreads();                        // drains vmcnt(0): buf0 ready

    for (int kt = 0; kt < nkt; ++kt) {
        if (kt + 1 < nkt) STAGE_TILE(cur ^ 1, kt + 1);   // overlaps compute below

        s16x8 bfr[4][2];
#pragma unroll
        for (int fn = 0; fn < 4; ++fn) {
            int lr = wn * 64 + fn * 16 + lrow;
            const short* bptr = &sB[cur][lr * 64];
            int sl0 = jhi ^ (lr & 7);
            bfr[fn][0] = *(const s16x8*)&bptr[sl0 << 3];
            bfr[fn][1] = *(const s16x8*)&bptr[(sl0 ^ 4) << 3];
        }
        __builtin_amdgcn_s_setprio(1);
#pragma unroll
        for (int fm = 0; fm < 8; ++fm) {
            int lr = wm * 128 + fm * 16 + lrow;
            const short* aptr = &sA[cur][lr * 64];
            int sl0 = jhi ^ (lr & 7);
            s16x8 a0 = *(const s16x8*)&aptr[sl0 << 3];
            s16x8 a1 = *(const s16x8*)&aptr[(sl0 ^ 4) << 3];
#pragma unroll
            for (int fn = 0; fn < 4; ++fn) {
                acc[fm][fn] = __builtin_amdgcn_mfma_f32_16x16x32_bf16(a0, bfr[fn][0], acc[fm][fn], 0, 0, 0);
                acc[fm][fn] = __builtin_amdgcn_mfma_f32_16x16x32_bf16(a1, bfr[fn][1], acc[fm][fn], 0, 0, 0);
            }
        }
        __builtin_amdgcn_s_setprio(0);
        __syncthreads();                    // retires cur reads + drains stage of cur^1
        cur ^= 1;
    }

    const int crow = (lane >> 4) * 4;
    const int ccol = lane & 15;

    if constexpr (EPI == 1) {
        float ssl[8][4] = {};
#pragma unroll
        for (int fm = 0; fm < 8; ++fm) {
#pragma unroll
            for (int fn = 0; fn < 4; ++fn) {
                int n = n0 + wn * 64 + fn * 16 + ccol;
                float b = bias[n];
#pragma unroll
                for (int r = 0; r < 4; ++r) {
                    float o = acc[fm][fn][r] + b;
                    ssl[fm][r] += o * o;
                    int m = m0 + wm * 128 + fm * 16 + crow + r;
                    if (m < M) C[(size_t)m * N + n] = (OutT)f2bf(fmaxf(o, 0.f));
                }
            }
        }
#pragma unroll
        for (int fm = 0; fm < 8; ++fm)
#pragma unroll
            for (int r = 0; r < 4; ++r) {
                float v = ssl[fm][r];
                v += __shfl_xor(v, 1); v += __shfl_xor(v, 2);
                v += __shfl_xor(v, 4); v += __shfl_xor(v, 8);
                int m = m0 + wm * 128 + fm * 16 + crow + r;
                if (ccol == 0 && m < M) atomicAdd(&ssbuf[m], v);
            }
    } else if constexpr (EPI == 2) {
        // row-scale: rinv computed here from raw sum-of-squares (rsqrt kernel folded in)
#pragma unroll
        for (int fm = 0; fm < 8; ++fm) {
#pragma unroll
            for (int r = 0; r < 4; ++r) {
                int m = m0 + wm * 128 + fm * 16 + crow + r;
                if (m >= M) continue;
                float sc = 1.0f / fmaxf(sqrtf(ssbuf[m]), 1e-12f);
#pragma unroll
                for (int fn = 0; fn < 4; ++fn) {
                    int n = n0 + wn * 64 + fn * 16 + ccol;
                    C[(size_t)m * N + n] = (OutT)f2bf(acc[fm][fn][r] * sc);
                }
            }
        }
    } else if constexpr (EPI == 3) {
        const int half = N >> 1;
#pragma unroll
        for (int fm = 0; fm < 8; ++fm) {
#pragma unroll
            for (int fn = 0; fn < 4; ++fn) {
                int n = n0 + wn * 64 + fn * 16 + ccol;
                bool hi = n >= half;
                float b = hi ? bias2[n - half] : bias[n];
                float* Cp = hi ? C2 : (float*)C;
                int nc = hi ? (n - half) : n;
#pragma unroll
                for (int r = 0; r < 4; ++r) {
                    int m = m0 + wm * 128 + fm * 16 + crow + r;
                    if (m < M) Cp[(size_t)m * half + nc] = acc[fm][fn][r] + b;
                }
            }
        }
    } else {
#pragma unroll
        for (int fm = 0; fm < 8; ++fm) {
#pragma unroll
            for (int fn = 0; fn < 4; ++fn) {
                int n = n0 + wn * 64 + fn * 16 + ccol;
                float b = ADD_BIAS ? bias[n] : 0.f;
#pragma unroll
                for (int r = 0; r < 4; ++r) {
                    int m = m0 + wm * 128 + fm * 16 + crow + r;
                    if (m < M) {
                        float o = acc[fm][fn][r] + b;
                        if constexpr (sizeof(OutT) == 2) C[(size_t)m * N + n] = (OutT)f2bf(o);
                        else                             C[(size_t)m * N + n] = o;
                    }
                }
            }
        }
    }
}

// ---------------- pooling stage 1: 1875 blocks x 8 row-pairs ----------------
__global__ __launch_bounds__(256) void pool_partial(const float* __restrict__ mu,
                                                    const float* __restrict__ lv,
                                                    const uint32_t* __restrict__ beta_p,
                                                    float* __restrict__ pmax,
                                                    float* __restrict__ psum) {
    uint32_t bb = beta_p[0];
    float beta = (bb & 0x7F800000u) ? __uint_as_float(bb) : (float)(int)bb;
    int b = blockIdx.x;
    int r0 = b * PP_ROWS;
    int r1 = min(r0 + PP_ROWS, HALF_ROWS);
    int c = threadIdx.x * 2;
    float m0 = -INFINITY, m1 = -INFINITY, s0 = 0.f, s1 = 0.f;
    for (int r = r0; r < r1; ++r) {
        size_t ia = (size_t)r * HDIM + c;
        size_t ib = (size_t)(r + HALF_ROWS) * HDIM + c;
        float2 mua = *(const float2*)&mu[ia];
        float2 lva = *(const float2*)&lv[ia];
        float2 mub = *(const float2*)&mu[ib];
        float2 lvb = *(const float2*)&lv[ib];
        uint32_t idx0 = (uint32_t)r * 512u + (uint32_t)c;
        uint32_t xa0 = idx0,     ya0 = idx0 + HALF_ELEMS;
        uint32_t xa1 = idx0 + 1, ya1 = idx0 + 1 + HALF_ELEMS;
        threefry2x32(0u, 42u, xa0, ya0);
        threefry2x32(0u, 42u, xa1, ya1);
        float za0 = mua.x + 0.01f * jax_normal(xa0) * __expf(0.5f * beta * lva.x);
        float zb0 = mub.x + 0.01f * jax_normal(ya0) * __expf(0.5f * beta * lvb.x);
        float za1 = mua.y + 0.01f * jax_normal(xa1) * __expf(0.5f * beta * lva.y);
        float zb1 = mub.y + 0.01f * jax_normal(ya1) * __expf(0.5f * beta * lvb.y);
        m0 = fmaxf(m0, fmaxf(za0, zb0)); s0 += za0 + zb0;
        m1 = fmaxf(m1, fmaxf(za1, zb1)); s1 += za1 + zb1;
    }
    pmax[(size_t)b * HDIM + c]     = m0;
    pmax[(size_t)b * HDIM + c + 1] = m1;
    psum[(size_t)b * HDIM + c]     = s0;
    psum[(size_t)b * HDIM + c + 1] = s1;
}

// ---------------- pooling stage 2: 1875 -> 63 partials ----------------
__global__ __launch_bounds__(256) void pool_mid(const float* __restrict__ pmax,
                                                const float* __restrict__ psum,
                                                float* __restrict__ pmax2,
                                                float* __restrict__ psum2) {
    int g = blockIdx.x;
    int b0 = g * 30;
    int b1 = min(b0 + 30, PP_BLOCKS);
#pragma unroll
    for (int pass = 0; pass < 2; ++pass) {
        int c = threadIdx.x + pass * 256;
        float m = -INFINITY, s = 0.f;
        for (int b = b0; b < b1; ++b) {
            m = fmaxf(m, pmax[(size_t)b * HDIM + c]);
            s += psum[(size_t)b * HDIM + c];
        }
        pmax2[(size_t)g * HDIM + c] = m;
        psum2[(size_t)g * HDIM + c] = s;
    }
}

// ---------------- pooling stage 3: 63 -> pooled[1024] ----------------
__global__ void pool_final(const float* __restrict__ pmax2, const float* __restrict__ psum2,
                           float* __restrict__ pooled) {
    int c = blockIdx.x * 256 + threadIdx.x;
    if (c < HDIM) {
        float m = -INFINITY, s = 0.f;
#pragma unroll
        for (int b = 0; b < PM_BLOCKS; ++b) {
            m = fmaxf(m, pmax2[(size_t)b * HDIM + c]);
            s += psum2[(size_t)b * HDIM + c];
        }
        pooled[c] = m;
        pooled[HDIM + c] = s / 30000.0f;
    }
}

// ---------------- decoder: split-K partial + finalize ----------------
__global__ __launch_bounds__(256) void dense_partial(const float* __restrict__ in,
                                                     const float* __restrict__ W,
                                                     float* __restrict__ part) {
    int by = blockIdx.y;                           // k-slice 0..7 (128 rows each)
    int j = blockIdx.x * 256 + threadIdx.x;        // 0..1023
    __shared__ float sin_[128];
    if (threadIdx.x < 128) sin_[threadIdx.x] = in[by * 128 + threadIdx.x];
    __syncthreads();
    float acc = 0.f;
#pragma unroll 8
    for (int i = 0; i < 128; ++i)
        acc = fmaf(sin_[i], W[(size_t)(by * 128 + i) * 1024 + j], acc);
    part[(size_t)by * 1024 + j] = acc;
}

__global__ void dense_final(const float* __restrict__ part, const float* __restrict__ bias,
                            float* __restrict__ out, int act) {
    int j = blockIdx.x * 256 + threadIdx.x;
    float acc = bias[j];
#pragma unroll
    for (int s = 0; s < 8; ++s) acc += part[(size_t)s * 1024 + j];
    out[j] = act ? (1.0f / (1.0f + __expf(-acc))) : fmaxf(acc, 0.f);
}

// ---------------- launch ----------------
extern "C" void kernel_launch(void* const* d_in, const int* in_sizes, int n_in,
                              void* d_out, int out_size, void* d_ws, size_t ws_size,
                              hipStream_t stream) {
    const float* x   = (const float*)d_in[0];
    const int*   ei  = (const int*)d_in[1];
    const float* ew  = (const float*)d_in[2];
    const uint32_t* beta = (const uint32_t*)d_in[3];
    const float* W1  = (const float*)d_in[4];
    const float* b1  = (const float*)d_in[5];
    const float* W2  = (const float*)d_in[6];
    const float* b2  = (const float*)d_in[7];
    const float* W3  = (const float*)d_in[8];
    const float* b3  = (const float*)d_in[9];
    const float* Wmu = (const float*)d_in[10];
    const float* bmu = (const float*)d_in[11];
    const float* Wlv = (const float*)d_in[12];
    const float* blv = (const float*)d_in[13];
    const float* Wd1 = (const float*)d_in[14];
    const float* bd1 = (const float*)d_in[15];
    const float* Wd2 = (const float*)d_in[16];
    const float* bd2 = (const float*)d_in[17];

    const int E = in_sizes[2];            // 300000
    const int M = NNODE;

    float* out    = (float*)d_out;
    float* mu_out = out + 1024;                           // [30000,512]
    float* lv_out = out + 1024 + (size_t)M * HDIM;        // [30000,512]

    // ---------------- workspace layout (bytes); no trailing backslashes in comments ----
    char* Wp = (char*)d_ws;
    short* slotA  = (short*)(Wp);                         // 61,603,840 B
    short* slotB  = (short*)(Wp + 61603840);              // 61,603,840 B
    short* xb     = (short*)(Wp + 123207680);             // 30,720,000 B
    short* W1t    = (short*)(Wp + 154009600);             // 1024x512
    short* W2t    = (short*)(Wp + 155058176);             // 512x1024
    short* W3t    = (short*)(Wp + 156106752);             // 256x512
    short* Wmut   = (short*)(Wp + 156368896);             // 512x256 (Wlvt MUST follow)
    short* Wlvt   = (short*)(Wp + 156631040);             // 512x256 = Wmut + 262144 B
    float* deg    = (float*)(Wp + 156893184);             // 120,000 B (memset group start)
    float* dinv   = (float*)(Wp + 157013184);             // 120,000 B
    int*   cnt    = (int*)  (Wp + 157133184);             // 120,000 B
    int*   fill   = (int*)  (Wp + 157253184);             // 120,000 B
    float* ssbuf  = (float*)(Wp + 157373184);             // 120,000 B (memset group end)
    int*   rowptr = (int*)  (Wp + 157493184);             // 120,004 B
    int*   ecol   = (int*)  (Wp + 157613188);             // 1,200,000 B
    float* eval   = (float*)(Wp + 158813188);             // 1,200,000 B
    float* pmax   = (float*)(Wp + 160013188);             // 1875*512*4 = 3,840,000 B
    float* psum   = (float*)(Wp + 163853188);             // 3,840,000 B
    float* pmax2  = (float*)(Wp + 167693188);             // 63*512*4 = 129,024 B
    float* psum2  = (float*)(Wp + 167822212);             // 129,024 B
    float* pooled = (float*)(Wp + 167951236);             // 4,096 B
    float* hdec   = (float*)(Wp + 167955332);             // 4,096 B
    float* dpart  = (float*)(Wp + 167959428);             // 32,768 B (ends ~168.0 MB)
    int*   bsum   = (int*)pmax;                           // scan scratch; pmax unused until pooling

    const int* row = ei;
    const int* col = ei + E;

    // 1) one memset for deg|dinv|cnt|fill|ssbuf
    hipMemsetAsync(deg, 0, 600000, stream);

    deg_cnt_kernel<<<(E + 255) / 256, 256, 0, stream>>>(row, ew, deg, cnt, E);
    dinv_kernel<<<(M + 255) / 256, 256, 0, stream>>>(deg, dinv, M);
    rp_blocksum<<<NSCAN, 256, 0, stream>>>(cnt, bsum);
    rp_scan<<<1, 128, 0, stream>>>(bsum, NSCAN);
    rp_write<<<NSCAN, 256, 0, stream>>>(cnt, bsum, rowptr, E);
    scatter_edges<<<(E + 255) / 256, 256, 0, stream>>>(row, col, ew, dinv, rowptr, fill,
                                                       ecol, eval, E);

    // 2) conversions: x -> bf16, weights -> transposed bf16 [N][K]
    f32_to_bf16<<<(M * FIN / 4 + 255) / 256, 256, 0, stream>>>(x, xb, M * FIN / 4);
    {
        dim3 b(256);
        transpose_bf16<<<dim3(H1DIM / 32, FIN / 32),   b, 0, stream>>>(W1,  W1t,  FIN,   H1DIM);
        transpose_bf16<<<dim3(H2DIM / 32, H1DIM / 32), b, 0, stream>>>(W2,  W2t,  H1DIM, H2DIM);
        transpose_bf16<<<dim3(H3DIM / 32, H2DIM / 32), b, 0, stream>>>(W3,  W3t,  H2DIM, H3DIM);
        transpose_bf16<<<dim3(HDIM / 32,  H3DIM / 32), b, 0, stream>>>(Wmu, Wmut, H3DIM, HDIM);
        transpose_bf16<<<dim3(HDIM / 32,  H3DIM / 32), b, 0, stream>>>(Wlv, Wlvt, H3DIM, HDIM);
    }

    const int SPMM_GRID = (M + 3) / 4;

    // 3) layer 1: AXb = A_hat@xb (slotA); relu_h1 + row-ss = AXb@W1t+b1 (slotB, EPI1)
    spmm_bf16<512, false><<<SPMM_GRID, 256, 0, stream>>>(rowptr, ecol, eval, dinv, xb,
                                                         nullptr, slotA);
    gemm_bf16<short, true, 1><<<(H1DIM / 256) * NPANEL, 512, 0, stream>>>(
        slotA, W1t, b1, nullptr, slotB, nullptr, ssbuf, M, H1DIM, FIN);

    // 4) layer 2: h2 = (relu_h1 @ W2t) * rinv[row] (slotA, EPI2 w/ inline rsqrt);
    //    out2 = fused spmm (slotB)
    gemm_bf16<short, false, 2><<<(H2DIM / 256) * NPANEL, 512, 0, stream>>>(
        slotB, W2t, nullptr, nullptr, slotA, nullptr, ssbuf, M, H2DIM, H1DIM);
    spmm_bf16<512, true><<<SPMM_GRID, 256, 0, stream>>>(rowptr, ecol, eval, dinv, slotA,
                                                        b2, slotB);

    // 5) layer 3: h3 = out2@W3t (slotA); out3 = fused spmm (slotB)
    gemm_bf16<short, false, 0><<<(H3DIM / 256) * NPANEL, 512, 0, stream>>>(
        slotB, W3t, nullptr, nullptr, slotA, nullptr, nullptr, M, H3DIM, H2DIM);
    spmm_bf16<256, true><<<SPMM_GRID, 256, 0, stream>>>(rowptr, ecol, eval, dinv, slotA,
                                                        b3, slotB);

    // 6) mu / logvar in ONE GEMM (Bt = [Wmut;Wlvt] contiguous, N=1024, split epilogue)
    gemm_bf16<float, true, 3><<<((2 * HDIM) / 256) * NPANEL, 512, 0, stream>>>(
        slotB, Wmut, bmu, blv, mu_out, lv_out, nullptr, M, 2 * HDIM, H3DIM);

    // 7) pooling with JAX-exact reparameterization noise (3-stage tree)
    pool_partial<<<PP_BLOCKS, 256, 0, stream>>>(mu_out, lv_out, beta, pmax, psum);
    pool_mid<<<PM_BLOCKS, 256, 0, stream>>>(pmax, psum, pmax2, psum2);
    pool_final<<<2, 256, 0, stream>>>(pmax2, psum2, pooled);

    // 8) decoder (split-K)
    dense_partial<<<dim3(4, 8), 256, 0, stream>>>(pooled, Wd1, dpart);
    dense_final<<<4, 256, 0, stream>>>(dpart, bd1, hdec, 0);
    dense_partial<<<dim3(4, 8), 256, 0, stream>>>(hdec, Wd2, dpart);
    dense_final<<<4, 256, 0, stream>>>(dpart, bd2, out, 1);
}

// Round 12
// 465.862 us; speedup vs baseline: 1.0565x; 1.0372x over previous
//
#include <hip/hip_runtime.h>
#include <cstdint>
#include <cstddef>

// ---------------- problem constants ----------------
#define NNODE      30000
#define FIN        512
#define H1DIM      1024
#define H2DIM      512
#define H3DIM      256
#define HDIM       512          // mu/logvar width
#define HALF_ROWS  15000
#define HALF_ELEMS 7680000u     // 15000*512 (threefry pair offset)
#define PP_ROWS    8
#define PP_BLOCKS  1875         // 15000/8
#define PM_BLOCKS  63           // mid-reduce blocks (30 pp-blocks each)
#define NPANEL     118          // ceil(30000/256) M-panels (BM=256)
#define NSCAN      118          // ceil(30000/256) scan blocks

typedef __attribute__((ext_vector_type(8))) short s16x8;
typedef __attribute__((ext_vector_type(4))) short s16x4;
typedef __attribute__((ext_vector_type(4))) float f32x4;

// bf16 <-> f32 (RNE, matches JAX/torch)
__device__ __forceinline__ short f2bf(float f) {
    uint32_t u = __float_as_uint(f);
    uint32_t r = (u + 0x7FFFu + ((u >> 16) & 1u)) >> 16;
    return (short)r;
}
__device__ __forceinline__ float bf2f(short s) {
    return __uint_as_float(((uint32_t)(uint16_t)s) << 16);
}

// ---------------- threefry2x32 (JAX-exact) ----------------
__device__ __forceinline__ void threefry2x32(uint32_t k0, uint32_t k1,
                                             uint32_t& x0, uint32_t& x1) {
    uint32_t ks0 = k0, ks1 = k1, ks2 = k0 ^ k1 ^ 0x1BD11BDAu;
    const uint32_t R0[4] = {13u, 15u, 26u, 6u};
    const uint32_t R1[4] = {17u, 29u, 16u, 24u};
    x0 += ks0; x1 += ks1;
#pragma unroll
    for (int g = 0; g < 5; ++g) {
        const uint32_t* R = (g & 1) ? R1 : R0;
#pragma unroll
        for (int r = 0; r < 4; ++r) {
            x0 += x1;
            x1 = (x1 << R[r]) | (x1 >> (32u - R[r]));
            x1 ^= x0;
        }
        uint32_t ks_a = (g % 3 == 0) ? ks1 : (g % 3 == 1 ? ks2 : ks0);
        uint32_t ks_b = (g % 3 == 0) ? ks2 : (g % 3 == 1 ? ks0 : ks1);
        x0 += ks_a;
        x1 += ks_b + (uint32_t)(g + 1);
    }
}

__device__ __forceinline__ float jax_normal(uint32_t bits) {
    uint32_t fb = (bits >> 9) | 0x3F800000u;
    float f = __uint_as_float(fb) - 1.0f;
    const float lo = -0.99999994f;
    float u = fmaf(f, 2.0f, lo);
    u = fmaxf(u, lo);
    return 1.41421356237f * erfinvf(u);
}

// ---------------- degree + count ----------------
__global__ void deg_cnt_kernel(const int* __restrict__ row, const float* __restrict__ w,
                               float* __restrict__ deg, int* __restrict__ cnt, int E) {
    int e = blockIdx.x * 256 + threadIdx.x;
    if (e < E) {
        int r = row[e];
        atomicAdd(&deg[r], w[e]);
        atomicAdd(&cnt[r], 1);
    }
}

// ---------------- parallel rowptr build: blocksum -> scan -> write ----------------
__global__ __launch_bounds__(256) void rp_blocksum(const int* __restrict__ cnt,
                                                   int* __restrict__ bsum) {
    __shared__ int sh[256];
    int i = blockIdx.x * 256 + threadIdx.x;
    sh[threadIdx.x] = (i < NNODE) ? cnt[i] : 0;
    __syncthreads();
    for (int o = 128; o; o >>= 1) {
        if (threadIdx.x < o) sh[threadIdx.x] += sh[threadIdx.x + o];
        __syncthreads();
    }
    if (threadIdx.x == 0) bsum[blockIdx.x] = sh[0];
}

__global__ __launch_bounds__(128) void rp_scan(int* __restrict__ bsum, int nb) {
    __shared__ int sh[128];
    int t = threadIdx.x;
    sh[t] = (t < nb) ? bsum[t] : 0;
    __syncthreads();
    for (int o = 1; o < 128; o <<= 1) {
        int v = (t >= o) ? sh[t - o] : 0;
        __syncthreads();
        sh[t] += v;
        __syncthreads();
    }
    if (t < nb) bsum[t] = (t == 0) ? 0 : sh[t - 1];   // exclusive
}

__global__ __launch_bounds__(256) void rp_write(const int* __restrict__ cnt,
                                                const int* __restrict__ bsum,
                                                int* __restrict__ rowptr, int E) {
    __shared__ int sh[256];
    int i = blockIdx.x * 256 + threadIdx.x;
    int v = (i < NNODE) ? cnt[i] : 0;
    sh[threadIdx.x] = v;
    __syncthreads();
    for (int o = 1; o < 256; o <<= 1) {
        int x = (threadIdx.x >= o) ? sh[threadIdx.x - o] : 0;
        __syncthreads();
        sh[threadIdx.x] += x;
        __syncthreads();
    }
    if (i < NNODE) rowptr[i] = bsum[blockIdx.x] + sh[threadIdx.x] - v;  // exclusive
    if (i == NNODE - 1) rowptr[NNODE] = E;
}

// ---------------- scatter edges into CSR; dinv computed inline from deg ----------------
__global__ void scatter_edges(const int* __restrict__ row, const int* __restrict__ col,
                              const float* __restrict__ w, const float* __restrict__ deg,
                              const int* __restrict__ rowptr, int* __restrict__ fill,
                              int* __restrict__ ecol, float* __restrict__ eval, int E) {
    int e = blockIdx.x * 256 + threadIdx.x;
    if (e < E) {
        int r = row[e], c = col[e];
        int pos = rowptr[r] + atomicAdd(&fill[r], 1);
        ecol[pos] = c;
        eval[pos] = rsqrtf(deg[r] + 1.0f) * w[e] * rsqrtf(deg[c] + 1.0f);
    }
}

// ---------------- batched prep: 5 weight transposes + x f32->bf16 in ONE kernel --------
__device__ __forceinline__ void tr32(float (*t)[33], const float* __restrict__ W,
                                     short* __restrict__ Wt, int K, int N, int kb, int nb) {
    int tx = threadIdx.x & 31, ty = threadIdx.x >> 5;     // 32 x 8
#pragma unroll
    for (int i = 0; i < 32; i += 8)
        if (kb + ty + i < K && nb + tx < N)
            t[ty + i][tx] = W[(size_t)(kb + ty + i) * N + nb + tx];
    __syncthreads();
#pragma unroll
    for (int i = 0; i < 32; i += 8)
        if (nb + ty + i < N && kb + tx < K)
            Wt[(size_t)(nb + ty + i) * K + kb + tx] = f2bf(t[tx][ty + i]);
}

__global__ __launch_bounds__(256) void prep_batched(const float* __restrict__ W1,
                                                    const float* __restrict__ W2,
                                                    const float* __restrict__ W3,
                                                    const float* __restrict__ Wmu,
                                                    const float* __restrict__ Wlv,
                                                    const float* __restrict__ x,
                                                    short* __restrict__ W1t,
                                                    short* __restrict__ W2t,
                                                    short* __restrict__ W3t,
                                                    short* __restrict__ Wmut,
                                                    short* __restrict__ Wlvt,
                                                    short* __restrict__ xb) {
    __shared__ float t[32][33];
    int bid = blockIdx.x;
    if (bid < 512) {                              // W1: K=512, N=1024 (32 x 16 blocks)
        tr32(t, W1, W1t, FIN, H1DIM, (bid >> 5) * 32, (bid & 31) * 32);
    } else if (bid < 1024) {                      // W2: K=1024, N=512 (16 x 32)
        int b = bid - 512;
        tr32(t, W2, W2t, H1DIM, H2DIM, (b >> 4) * 32, (b & 15) * 32);
    } else if (bid < 1152) {                      // W3: K=512, N=256 (8 x 16)
        int b = bid - 1024;
        tr32(t, W3, W3t, H2DIM, H3DIM, (b >> 3) * 32, (b & 7) * 32);
    } else if (bid < 1280) {                      // Wmu: K=256, N=512 (16 x 8)
        int b = bid - 1152;
        tr32(t, Wmu, Wmut, H3DIM, HDIM, (b >> 4) * 32, (b & 15) * 32);
    } else if (bid < 1408) {                      // Wlv
        int b = bid - 1280;
        tr32(t, Wlv, Wlvt, H3DIM, HDIM, (b >> 4) * 32, (b & 15) * 32);
    } else {                                      // x convert: 15000 blocks of 256 float4
        int i = (bid - 1408) * 256 + threadIdx.x; // i < 3,840,000
        float4 v = ((const float4*)x)[i];
        s16x4 s = { f2bf(v.x), f2bf(v.y), f2bf(v.z), f2bf(v.w) };
        *(s16x4*)(xb + (size_t)i * 4) = s;
    }
}

// ---------------- CSR SpMM on bf16 rows; 4x-unrolled edge loop; deg-inline dinv --------
template <int F, bool FUSE>
__global__ __launch_bounds__(256) void spmm_bf16(const int* __restrict__ rowptr,
                                                 const int* __restrict__ ecol,
                                                 const float* __restrict__ eval,
                                                 const float* __restrict__ deg,
                                                 const short* __restrict__ h,
                                                 const float* __restrict__ bias,
                                                 short* __restrict__ out) {
    constexpr int NE = F / 64;               // 512->8, 256->4
    int lane = threadIdx.x & 63;
    int r = blockIdx.x * 4 + (threadIdx.x >> 6);
    if (r >= NNODE) return;
    float dd = 1.0f / (deg[r] + 1.0f);       // dinv^2 (<=2ulp vs rsqrtf^2; absorbed by bf16)
    float acc[NE];
    {
        const short* p = h + (size_t)r * F + lane * NE;
        if constexpr (NE == 8) {
            s16x8 v = *(const s16x8*)p;
#pragma unroll
            for (int j = 0; j < 8; ++j) acc[j] = dd * bf2f(v[j]);
        } else {
            s16x4 v = *(const s16x4*)p;
#pragma unroll
            for (int j = 0; j < 4; ++j) acc[j] = dd * bf2f(v[j]);
        }
    }
    int e0 = rowptr[r], e1 = rowptr[r + 1];
    int e = e0;
    for (; e + 4 <= e1; e += 4) {
        int   c0 = ecol[e],     c1 = ecol[e + 1], c2 = ecol[e + 2], c3 = ecol[e + 3];
        float w0 = eval[e],     w1 = eval[e + 1], w2 = eval[e + 2], w3 = eval[e + 3];
        const short* p0 = h + (size_t)c0 * F + lane * NE;
        const short* p1 = h + (size_t)c1 * F + lane * NE;
        const short* p2 = h + (size_t)c2 * F + lane * NE;
        const short* p3 = h + (size_t)c3 * F + lane * NE;
        if constexpr (NE == 8) {
            s16x8 v0 = *(const s16x8*)p0;
            s16x8 v1 = *(const s16x8*)p1;
            s16x8 v2 = *(const s16x8*)p2;
            s16x8 v3 = *(const s16x8*)p3;
#pragma unroll
            for (int j = 0; j < 8; ++j) acc[j] = fmaf(w0, bf2f(v0[j]), acc[j]);
#pragma unroll
            for (int j = 0; j < 8; ++j) acc[j] = fmaf(w1, bf2f(v1[j]), acc[j]);
#pragma unroll
            for (int j = 0; j < 8; ++j) acc[j] = fmaf(w2, bf2f(v2[j]), acc[j]);
#pragma unroll
            for (int j = 0; j < 8; ++j) acc[j] = fmaf(w3, bf2f(v3[j]), acc[j]);
        } else {
            s16x4 v0 = *(const s16x4*)p0;
            s16x4 v1 = *(const s16x4*)p1;
            s16x4 v2 = *(const s16x4*)p2;
            s16x4 v3 = *(const s16x4*)p3;
#pragma unroll
            for (int j = 0; j < 4; ++j) acc[j] = fmaf(w0, bf2f(v0[j]), acc[j]);
#pragma unroll
            for (int j = 0; j < 4; ++j) acc[j] = fmaf(w1, bf2f(v1[j]), acc[j]);
#pragma unroll
            for (int j = 0; j < 4; ++j) acc[j] = fmaf(w2, bf2f(v2[j]), acc[j]);
#pragma unroll
            for (int j = 0; j < 4; ++j) acc[j] = fmaf(w3, bf2f(v3[j]), acc[j]);
        }
    }
    for (; e < e1; ++e) {
        int c = ecol[e];
        float nw = eval[e];
        const short* p = h + (size_t)c * F + lane * NE;
        if constexpr (NE == 8) {
            s16x8 v = *(const s16x8*)p;
#pragma unroll
            for (int j = 0; j < 8; ++j) acc[j] = fmaf(nw, bf2f(v[j]), acc[j]);
        } else {
            s16x4 v = *(const s16x4*)p;
#pragma unroll
            for (int j = 0; j < 4; ++j) acc[j] = fmaf(nw, bf2f(v[j]), acc[j]);
        }
    }
    short* o = out + (size_t)r * F + lane * NE;
    if (FUSE) {
        const float* bp = bias + lane * NE;
        float ss = 0.f;
#pragma unroll
        for (int j = 0; j < NE; ++j) { acc[j] += bp[j]; ss += acc[j] * acc[j]; }
#pragma unroll
        for (int off = 32; off; off >>= 1) ss += __shfl_xor(ss, off);
        float rinv = 1.0f / fmaxf(sqrtf(ss), 1e-12f);
#pragma unroll
        for (int j = 0; j < NE; ++j) acc[j] = fmaxf(acc[j] * rinv, 0.f);
    }
    if constexpr (NE == 8) {
        s16x8 s;
#pragma unroll
        for (int j = 0; j < 8; ++j) s[j] = f2bf(acc[j]);
        *(s16x8*)o = s;
    } else {
        s16x4 s;
#pragma unroll
        for (int j = 0; j < 4; ++j) s[j] = f2bf(acc[j]);
        *(s16x4*)o = s;
    }
}

// ---------------- stage one 64-wide K-tile (256 A-rows + 256 B-rows) into LDS ----------
#define STAGE_TILE(buf_, kt_)                                                              \
  {                                                                                        \
    const int k0_ = (kt_) << 6;                                                            \
    _Pragma("unroll")                                                                      \
    for (int i_ = 0; i_ < 4; ++i_) {                                                       \
      int c_ = i_ * 8 + w;                                                                 \
      int tr_ = c_ * 8 + srow;                                                             \
      __builtin_amdgcn_global_load_lds(                                                    \
          (const __attribute__((address_space(1))) void*)(A + (size_t)(m0 + tr_) * K + k0_ + scol), \
          (__attribute__((address_space(3))) void*)(&sA[buf_][c_ * 512]), 16, 0, 0);       \
    }                                                                                      \
    _Pragma("unroll")                                                                      \
    for (int i_ = 0; i_ < 4; ++i_) {                                                       \
      int c_ = i_ * 8 + w;                                                                 \
      int tr_ = c_ * 8 + srow;                                                             \
      __builtin_amdgcn_global_load_lds(                                                    \
          (const __attribute__((address_space(1))) void*)(Bt + (size_t)(n0 + tr_) * K + k0_ + scol), \
          (__attribute__((address_space(3))) void*)(&sB[buf_][c_ * 512]), 16, 0, 0);       \
    }                                                                                      \
  }

// ---------------- bf16 MFMA GEMM: 256x256 tile, 2-phase dbuf, T2+XCD swizzle -----------
// EPI: 0 plain(+bias) | 1 bias+ReLU+row-SS atomics | 2 row-scale rinv(ssbuf) | 3 dual split
template <typename OutT, bool ADD_BIAS, int EPI>
__global__ __launch_bounds__(512) void gemm_bf16(const short* __restrict__ A,
                                                 const short* __restrict__ Bt,
                                                 const float* __restrict__ bias,
                                                 const float* __restrict__ bias2,
                                                 OutT* __restrict__ C,
                                                 float* __restrict__ C2,
                                                 float* __restrict__ ssbuf,
                                                 int M, int N, int K) {
    __shared__ short sA[2][256 * 64];
    __shared__ short sB[2][256 * 64];
    const int tid = threadIdx.x;
    const int lane = tid & 63;
    const int w = tid >> 6;                 // wave 0..7
    const int wm = w >> 2, wn = w & 3;      // 2M x 4N; per-wave 128 rows x 64 cols

    const int nwg = gridDim.x;
    const int orig = blockIdx.x;
    const int q = nwg >> 3, rr = nwg & 7;
    const int xcd = orig & 7;
    const int base = (xcd < rr) ? xcd * (q + 1) : rr * (q + 1) + (xcd - rr) * q;
    const int wgid = base + (orig >> 3);
    const int nx = N >> 8;                  // N-blocks of 256
    const int lg = __builtin_ctz(nx);
    const int pid = wgid >> lg;             // M-panel (256 rows)
    const int cblk = wgid & (nx - 1);
    const int m0 = pid << 8;
    const int n0 = cblk << 8;

    const int srow = lane >> 3;             // 0..7
    const int scol = ((lane & 7) ^ srow) * 8;   // T2 pre-swizzled source col

    f32x4 acc[8][4] = {};

    const int lrow = lane & 15;
    const int jhi = lane >> 4;              // 0..3

    const int nkt = K >> 6;
    int cur = 0;
    STAGE_TILE(0, 0);
    __syncthreads();

    for (int kt = 0; kt < nkt; ++kt) {
        if (kt + 1 < nkt) STAGE_TILE(cur ^ 1, kt + 1);

        s16x8 bfr[4][2];
#pragma unroll
        for (int fn = 0; fn < 4; ++fn) {
            int lr = wn * 64 + fn * 16 + lrow;
            const short* bptr = &sB[cur][lr * 64];
            int sl0 = jhi ^ (lr & 7);
            bfr[fn][0] = *(const s16x8*)&bptr[sl0 << 3];
            bfr[fn][1] = *(const s16x8*)&bptr[(sl0 ^ 4) << 3];
        }
        __builtin_amdgcn_s_setprio(1);
#pragma unroll
        for (int fm = 0; fm < 8; ++fm) {
            int lr = wm * 128 + fm * 16 + lrow;
            const short* aptr = &sA[cur][lr * 64];
            int sl0 = jhi ^ (lr & 7);
            s16x8 a0 = *(const s16x8*)&aptr[sl0 << 3];
            s16x8 a1 = *(const s16x8*)&aptr[(sl0 ^ 4) << 3];
#pragma unroll
            for (int fn = 0; fn < 4; ++fn) {
                acc[fm][fn] = __builtin_amdgcn_mfma_f32_16x16x32_bf16(a0, bfr[fn][0], acc[fm][fn], 0, 0, 0);
                acc[fm][fn] = __builtin_amdgcn_mfma_f32_16x16x32_bf16(a1, bfr[fn][1], acc[fm][fn], 0, 0, 0);
            }
        }
        __builtin_amdgcn_s_setprio(0);
        __syncthreads();
        cur ^= 1;
    }

    const int crow = (lane >> 4) * 4;
    const int ccol = lane & 15;

    if constexpr (EPI == 1) {
        float ssl[8][4] = {};
#pragma unroll
        for (int fm = 0; fm < 8; ++fm) {
#pragma unroll
            for (int fn = 0; fn < 4; ++fn) {
                int n = n0 + wn * 64 + fn * 16 + ccol;
                float b = bias[n];
#pragma unroll
                for (int r = 0; r < 4; ++r) {
                    float o = acc[fm][fn][r] + b;
                    ssl[fm][r] += o * o;
                    int m = m0 + wm * 128 + fm * 16 + crow + r;
                    if (m < M) C[(size_t)m * N + n] = (OutT)f2bf(fmaxf(o, 0.f));
                }
            }
        }
#pragma unroll
        for (int fm = 0; fm < 8; ++fm)
#pragma unroll
            for (int r = 0; r < 4; ++r) {
                float v = ssl[fm][r];
                v += __shfl_xor(v, 1); v += __shfl_xor(v, 2);
                v += __shfl_xor(v, 4); v += __shfl_xor(v, 8);
                int m = m0 + wm * 128 + fm * 16 + crow + r;
                if (ccol == 0 && m < M) atomicAdd(&ssbuf[m], v);
            }
    } else if constexpr (EPI == 2) {
#pragma unroll
        for (int fm = 0; fm < 8; ++fm) {
#pragma unroll
            for (int r = 0; r < 4; ++r) {
                int m = m0 + wm * 128 + fm * 16 + crow + r;
                if (m >= M) continue;
                float sc = 1.0f / fmaxf(sqrtf(ssbuf[m]), 1e-12f);
#pragma unroll
                for (int fn = 0; fn < 4; ++fn) {
                    int n = n0 + wn * 64 + fn * 16 + ccol;
                    C[(size_t)m * N + n] = (OutT)f2bf(acc[fm][fn][r] * sc);
                }
            }
        }
    } else if constexpr (EPI == 3) {
        const int half = N >> 1;
#pragma unroll
        for (int fm = 0; fm < 8; ++fm) {
#pragma unroll
            for (int fn = 0; fn < 4; ++fn) {
                int n = n0 + wn * 64 + fn * 16 + ccol;
                bool hi = n >= half;
                float b = hi ? bias2[n - half] : bias[n];
                float* Cp = hi ? C2 : (float*)C;
                int nc = hi ? (n - half) : n;
#pragma unroll
                for (int r = 0; r < 4; ++r) {
                    int m = m0 + wm * 128 + fm * 16 + crow + r;
                    if (m < M) Cp[(size_t)m * half + nc] = acc[fm][fn][r] + b;
                }
            }
        }
    } else {
#pragma unroll
        for (int fm = 0; fm < 8; ++fm) {
#pragma unroll
            for (int fn = 0; fn < 4; ++fn) {
                int n = n0 + wn * 64 + fn * 16 + ccol;
                float b = ADD_BIAS ? bias[n] : 0.f;
#pragma unroll
                for (int r = 0; r < 4; ++r) {
                    int m = m0 + wm * 128 + fm * 16 + crow + r;
                    if (m < M) {
                        float o = acc[fm][fn][r] + b;
                        if constexpr (sizeof(OutT) == 2) C[(size_t)m * N + n] = (OutT)f2bf(o);
                        else                             C[(size_t)m * N + n] = o;
                    }
                }
            }
        }
    }
}

// ---------------- pooling stage 1: 1875 blocks x 8 row-pairs ----------------
__global__ __launch_bounds__(256) void pool_partial(const float* __restrict__ mu,
                                                    const float* __restrict__ lv,
                                                    const uint32_t* __restrict__ beta_p,
                                                    float* __restrict__ pmax,
                                                    float* __restrict__ psum) {
    uint32_t bb = beta_p[0];
    float beta = (bb & 0x7F800000u) ? __uint_as_float(bb) : (float)(int)bb;
    int b = blockIdx.x;
    int r0 = b * PP_ROWS;
    int r1 = min(r0 + PP_ROWS, HALF_ROWS);
    int c = threadIdx.x * 2;
    float m0 = -INFINITY, m1 = -INFINITY, s0 = 0.f, s1 = 0.f;
    for (int r = r0; r < r1; ++r) {
        size_t ia = (size_t)r * HDIM + c;
        size_t ib = (size_t)(r + HALF_ROWS) * HDIM + c;
        float2 mua = *(const float2*)&mu[ia];
        float2 lva = *(const float2*)&lv[ia];
        float2 mub = *(const float2*)&mu[ib];
        float2 lvb = *(const float2*)&lv[ib];
        uint32_t idx0 = (uint32_t)r * 512u + (uint32_t)c;
        uint32_t xa0 = idx0,     ya0 = idx0 + HALF_ELEMS;
        uint32_t xa1 = idx0 + 1, ya1 = idx0 + 1 + HALF_ELEMS;
        threefry2x32(0u, 42u, xa0, ya0);
        threefry2x32(0u, 42u, xa1, ya1);
        float za0 = mua.x + 0.01f * jax_normal(xa0) * __expf(0.5f * beta * lva.x);
        float zb0 = mub.x + 0.01f * jax_normal(ya0) * __expf(0.5f * beta * lvb.x);
        float za1 = mua.y + 0.01f * jax_normal(xa1) * __expf(0.5f * beta * lva.y);
        float zb1 = mub.y + 0.01f * jax_normal(ya1) * __expf(0.5f * beta * lvb.y);
        m0 = fmaxf(m0, fmaxf(za0, zb0)); s0 += za0 + zb0;
        m1 = fmaxf(m1, fmaxf(za1, zb1)); s1 += za1 + zb1;
    }
    pmax[(size_t)b * HDIM + c]     = m0;
    pmax[(size_t)b * HDIM + c + 1] = m1;
    psum[(size_t)b * HDIM + c]     = s0;
    psum[(size_t)b * HDIM + c + 1] = s1;
}

// ---------------- pooling stage 2: 1875 -> 63 partials ----------------
__global__ __launch_bounds__(256) void pool_mid(const float* __restrict__ pmax,
                                                const float* __restrict__ psum,
                                                float* __restrict__ pmax2,
                                                float* __restrict__ psum2) {
    int g = blockIdx.x;
    int b0 = g * 30;
    int b1 = min(b0 + 30, PP_BLOCKS);
#pragma unroll
    for (int pass = 0; pass < 2; ++pass) {
        int c = threadIdx.x + pass * 256;
        float m = -INFINITY, s = 0.f;
        for (int b = b0; b < b1; ++b) {
            m = fmaxf(m, pmax[(size_t)b * HDIM + c]);
            s += psum[(size_t)b * HDIM + c];
        }
        pmax2[(size_t)g * HDIM + c] = m;
        psum2[(size_t)g * HDIM + c] = s;
    }
}

// ---------------- decoder stage 1: fused pool_final + dense_partial --------------------
// grid (4,8): block (bx,by) reduces pooled slice [by*128, by*128+128) from pmax2/psum2,
// then computes partial dot for outputs j in [bx*256, +256) over that K-slice.
__global__ __launch_bounds__(256) void dec1(const float* __restrict__ pmax2,
                                            const float* __restrict__ psum2,
                                            const float* __restrict__ W,
                                            float* __restrict__ part) {
    __shared__ float sin_[128];
    int by = blockIdx.y;
    if (threadIdx.x < 128) {
        int c = by * 128 + threadIdx.x;               // 0..1023
        float v;
        if (c < HDIM) {
            float m = -INFINITY;
            for (int b = 0; b < PM_BLOCKS; ++b) m = fmaxf(m, pmax2[(size_t)b * HDIM + c]);
            v = m;
        } else {
            int cc = c - HDIM;
            float s = 0.f;
            for (int b = 0; b < PM_BLOCKS; ++b) s += psum2[(size_t)b * HDIM + cc];
            v = s / 30000.0f;
        }
        sin_[threadIdx.x] = v;
    }
    __syncthreads();
    int j = blockIdx.x * 256 + threadIdx.x;
    float acc = 0.f;
#pragma unroll 8
    for (int i = 0; i < 128; ++i)
        acc = fmaf(sin_[i], W[(size_t)(by * 128 + i) * 1024 + j], acc);
    part[(size_t)by * 1024 + j] = acc;
}

// ---------------- decoder stage 2: fused dense_final(relu) + dense_partial -------------
// grid (4,8): block (bx,by) computes hdec slice [by*128,+128) = relu(bd1 + sum parts),
// then partial dot for outputs j in [bx*256,+256).
__global__ __launch_bounds__(256) void dec2(const float* __restrict__ part,
                                            const float* __restrict__ bd1,
                                            const float* __restrict__ W,
                                            float* __restrict__ part2) {
    __shared__ float sh[128];
    int by = blockIdx.y;
    if (threadIdx.x < 128) {
        int j2 = by * 128 + threadIdx.x;
        float v = bd1[j2];
#pragma unroll
        for (int s = 0; s < 8; ++s) v += part[(size_t)s * 1024 + j2];
        sh[threadIdx.x] = fmaxf(v, 0.f);
    }
    __syncthreads();
    int j = blockIdx.x * 256 + threadIdx.x;
    float acc = 0.f;
#pragma unroll 8
    for (int i = 0; i < 128; ++i)
        acc = fmaf(sh[i], W[(size_t)(by * 128 + i) * 1024 + j], acc);
    part2[(size_t)by * 1024 + j] = acc;
}

__global__ void dense_final(const float* __restrict__ part, const float* __restrict__ bias,
                            float* __restrict__ out) {
    int j = blockIdx.x * 256 + threadIdx.x;
    float acc = bias[j];
#pragma unroll
    for (int s = 0; s < 8; ++s) acc += part[(size_t)s * 1024 + j];
    out[j] = 1.0f / (1.0f + __expf(-acc));
}

// ---------------- launch ----------------
extern "C" void kernel_launch(void* const* d_in, const int* in_sizes, int n_in,
                              void* d_out, int out_size, void* d_ws, size_t ws_size,
                              hipStream_t stream) {
    const float* x   = (const float*)d_in[0];
    const int*   ei  = (const int*)d_in[1];
    const float* ew  = (const float*)d_in[2];
    const uint32_t* beta = (const uint32_t*)d_in[3];
    const float* W1  = (const float*)d_in[4];
    const float* b1  = (const float*)d_in[5];
    const float* W2  = (const float*)d_in[6];
    const float* b2  = (const float*)d_in[7];
    const float* W3  = (const float*)d_in[8];
    const float* b3  = (const float*)d_in[9];
    const float* Wmu = (const float*)d_in[10];
    const float* bmu = (const float*)d_in[11];
    const float* Wlv = (const float*)d_in[12];
    const float* blv = (const float*)d_in[13];
    const float* Wd1 = (const float*)d_in[14];
    const float* bd1 = (const float*)d_in[15];
    const float* Wd2 = (const float*)d_in[16];
    const float* bd2 = (const float*)d_in[17];

    const int E = in_sizes[2];            // 300000
    const int M = NNODE;

    float* out    = (float*)d_out;
    float* mu_out = out + 1024;                           // [30000,512]
    float* lv_out = out + 1024 + (size_t)M * HDIM;        // [30000,512]

    // ---------------- workspace layout (bytes); no trailing backslashes in comments ----
    char* Wp = (char*)d_ws;
    short* slotA  = (short*)(Wp);                         // 61,603,840 B
    short* slotB  = (short*)(Wp + 61603840);              // 61,603,840 B
    short* xb     = (short*)(Wp + 123207680);             // 30,720,000 B
    short* W1t    = (short*)(Wp + 154009600);             // 1024x512
    short* W2t    = (short*)(Wp + 155058176);             // 512x1024
    short* W3t    = (short*)(Wp + 156106752);             // 256x512
    short* Wmut   = (short*)(Wp + 156368896);             // 512x256 (Wlvt MUST follow)
    short* Wlvt   = (short*)(Wp + 156631040);             // 512x256 = Wmut + 262144 B
    float* deg    = (float*)(Wp + 156893184);             // 120,000 B (memset group start)
    float* spare  = (float*)(Wp + 157013184);             // 120,000 B (ex-dinv, unused)
    int*   cnt    = (int*)  (Wp + 157133184);             // 120,000 B
    int*   fill   = (int*)  (Wp + 157253184);             // 120,000 B
    float* ssbuf  = (float*)(Wp + 157373184);             // 120,000 B (memset group end)
    int*   rowptr = (int*)  (Wp + 157493184);             // 120,004 B
    int*   ecol   = (int*)  (Wp + 157613188);             // 1,200,000 B
    float* eval   = (float*)(Wp + 158813188);             // 1,200,000 B
    float* pmax   = (float*)(Wp + 160013188);             // 1875*512*4 = 3,840,000 B
    float* psum   = (float*)(Wp + 163853188);             // 3,840,000 B
    float* pmax2  = (float*)(Wp + 167693188);             // 63*512*4 = 129,024 B
    float* psum2  = (float*)(Wp + 167822212);             // 129,024 B
    float* dpart  = (float*)(Wp + 167951236);             // 8*1024*4 = 32,768 B
    float* dpart2 = (float*)(Wp + 167984004);             // 32,768 B (ends ~168.0 MB)
    int*   bsum   = (int*)pmax;                           // scan scratch; pmax unused until pooling
    (void)spare;

    const int* row = ei;
    const int* col = ei + E;

    // 1) one memset for deg|spare|cnt|fill|ssbuf
    hipMemsetAsync(deg, 0, 600000, stream);

    deg_cnt_kernel<<<(E + 255) / 256, 256, 0, stream>>>(row, ew, deg, cnt, E);
    rp_blocksum<<<NSCAN, 256, 0, stream>>>(cnt, bsum);
    rp_scan<<<1, 128, 0, stream>>>(bsum, NSCAN);
    rp_write<<<NSCAN, 256, 0, stream>>>(cnt, bsum, rowptr, E);
    scatter_edges<<<(E + 255) / 256, 256, 0, stream>>>(row, col, ew, deg, rowptr, fill,
                                                       ecol, eval, E);

    // 2) batched prep: 5 transposes + x convert in one kernel (1408 + 15000 blocks)
    prep_batched<<<16408, 256, 0, stream>>>(W1, W2, W3, Wmu, Wlv, x,
                                            W1t, W2t, W3t, Wmut, Wlvt, xb);

    const int SPMM_GRID = (M + 3) / 4;

    // 3) layer 1: AXb = A_hat@xb (slotA); relu_h1 + row-ss = AXb@W1t+b1 (slotB, EPI1)
    spmm_bf16<512, false><<<SPMM_GRID, 256, 0, stream>>>(rowptr, ecol, eval, deg, xb,
                                                         nullptr, slotA);
    gemm_bf16<short, true, 1><<<(H1DIM / 256) * NPANEL, 512, 0, stream>>>(
        slotA, W1t, b1, nullptr, slotB, nullptr, ssbuf, M, H1DIM, FIN);

    // 4) layer 2: h2 = (relu_h1 @ W2t) * rinv[row] (slotA, EPI2 inline rsqrt);
    //    out2 = fused spmm (slotB)
    gemm_bf16<short, false, 2><<<(H2DIM / 256) * NPANEL, 512, 0, stream>>>(
        slotB, W2t, nullptr, nullptr, slotA, nullptr, ssbuf, M, H2DIM, H1DIM);
    spmm_bf16<512, true><<<SPMM_GRID, 256, 0, stream>>>(rowptr, ecol, eval, deg, slotA,
                                                        b2, slotB);

    // 5) layer 3: h3 = out2@W3t (slotA); out3 = fused spmm (slotB)
    gemm_bf16<short, false, 0><<<(H3DIM / 256) * NPANEL, 512, 0, stream>>>(
        slotB, W3t, nullptr, nullptr, slotA, nullptr, nullptr, M, H3DIM, H2DIM);
    spmm_bf16<256, true><<<SPMM_GRID, 256, 0, stream>>>(rowptr, ecol, eval, deg, slotA,
                                                        b3, slotB);

    // 6) mu / logvar in ONE GEMM (Bt = [Wmut;Wlvt] contiguous, N=1024, split epilogue)
    gemm_bf16<float, true, 3><<<((2 * HDIM) / 256) * NPANEL, 512, 0, stream>>>(
        slotB, Wmut, bmu, blv, mu_out, lv_out, nullptr, M, 2 * HDIM, H3DIM);

    // 7) pooling (JAX-exact noise): partial -> mid; final fused into dec1
    pool_partial<<<PP_BLOCKS, 256, 0, stream>>>(mu_out, lv_out, beta, pmax, psum);
    pool_mid<<<PM_BLOCKS, 256, 0, stream>>>(pmax, psum, pmax2, psum2);

    // 8) decoder: dec1 (pool_final+partial), dec2 (relu-final+partial), final sigmoid
    dec1<<<dim3(4, 8), 256, 0, stream>>>(pmax2, psum2, Wd1, dpart);
    dec2<<<dim3(4, 8), 256, 0, stream>>>(dpart, bd1, Wd2, dpart2);
    dense_final<<<4, 256, 0, stream>>>(dpart2, bd2, out);
}

// Round 13
// 458.840 us; speedup vs baseline: 1.0727x; 1.0153x over previous
//
#include <hip/hip_runtime.h>
#include <cstdint>
#include <cstddef>

// ---------------- problem constants ----------------
#define NNODE      30000
#define FIN        512
#define H1DIM      1024
#define H2DIM      512
#define H3DIM      256
#define HDIM       512          // mu/logvar width
#define HALF_ROWS  15000
#define HALF_ELEMS 7680000u     // 15000*512 (threefry pair offset)
#define PP_ROWS    8
#define PP_BLOCKS  1875         // 15000/8
#define PM_BLOCKS  63           // mid-reduce blocks (30 pp-blocks each)
#define NPANEL     118          // ceil(30000/256) M-panels (BM=256)
#define NSCAN      118          // ceil(30000/256) scan blocks

typedef __attribute__((ext_vector_type(8))) short s16x8;
typedef __attribute__((ext_vector_type(4))) short s16x4;
typedef __attribute__((ext_vector_type(4))) float f32x4;

// bf16 <-> f32 (RNE, matches JAX/torch)
__device__ __forceinline__ short f2bf(float f) {
    uint32_t u = __float_as_uint(f);
    uint32_t r = (u + 0x7FFFu + ((u >> 16) & 1u)) >> 16;
    return (short)r;
}
__device__ __forceinline__ float bf2f(short s) {
    return __uint_as_float(((uint32_t)(uint16_t)s) << 16);
}

// ---------------- threefry2x32 (JAX-exact) ----------------
__device__ __forceinline__ void threefry2x32(uint32_t k0, uint32_t k1,
                                             uint32_t& x0, uint32_t& x1) {
    uint32_t ks0 = k0, ks1 = k1, ks2 = k0 ^ k1 ^ 0x1BD11BDAu;
    const uint32_t R0[4] = {13u, 15u, 26u, 6u};
    const uint32_t R1[4] = {17u, 29u, 16u, 24u};
    x0 += ks0; x1 += ks1;
#pragma unroll
    for (int g = 0; g < 5; ++g) {
        const uint32_t* R = (g & 1) ? R1 : R0;
#pragma unroll
        for (int r = 0; r < 4; ++r) {
            x0 += x1;
            x1 = (x1 << R[r]) | (x1 >> (32u - R[r]));
            x1 ^= x0;
        }
        uint32_t ks_a = (g % 3 == 0) ? ks1 : (g % 3 == 1 ? ks2 : ks0);
        uint32_t ks_b = (g % 3 == 0) ? ks2 : (g % 3 == 1 ? ks0 : ks1);
        x0 += ks_a;
        x1 += ks_b + (uint32_t)(g + 1);
    }
}

__device__ __forceinline__ float jax_normal(uint32_t bits) {
    uint32_t fb = (bits >> 9) | 0x3F800000u;
    float f = __uint_as_float(fb) - 1.0f;
    const float lo = -0.99999994f;
    float u = fmaf(f, 2.0f, lo);
    u = fmaxf(u, lo);
    return 1.41421356237f * erfinvf(u);
}

// ---------------- degree + count ----------------
__global__ void deg_cnt_kernel(const int* __restrict__ row, const float* __restrict__ w,
                               float* __restrict__ deg, int* __restrict__ cnt, int E) {
    int e = blockIdx.x * 256 + threadIdx.x;
    if (e < E) {
        int r = row[e];
        atomicAdd(&deg[r], w[e]);
        atomicAdd(&cnt[r], 1);
    }
}

// ---------------- parallel rowptr build: blocksum -> scan -> write ----------------
__global__ __launch_bounds__(256) void rp_blocksum(const int* __restrict__ cnt,
                                                   int* __restrict__ bsum) {
    __shared__ int sh[256];
    int i = blockIdx.x * 256 + threadIdx.x;
    sh[threadIdx.x] = (i < NNODE) ? cnt[i] : 0;
    __syncthreads();
    for (int o = 128; o; o >>= 1) {
        if (threadIdx.x < o) sh[threadIdx.x] += sh[threadIdx.x + o];
        __syncthreads();
    }
    if (threadIdx.x == 0) bsum[blockIdx.x] = sh[0];
}

__global__ __launch_bounds__(128) void rp_scan(int* __restrict__ bsum, int nb) {
    __shared__ int sh[128];
    int t = threadIdx.x;
    sh[t] = (t < nb) ? bsum[t] : 0;
    __syncthreads();
    for (int o = 1; o < 128; o <<= 1) {
        int v = (t >= o) ? sh[t - o] : 0;
        __syncthreads();
        sh[t] += v;
        __syncthreads();
    }
    if (t < nb) bsum[t] = (t == 0) ? 0 : sh[t - 1];   // exclusive
}

__global__ __launch_bounds__(256) void rp_write(const int* __restrict__ cnt,
                                                const int* __restrict__ bsum,
                                                int* __restrict__ rowptr, int E) {
    __shared__ int sh[256];
    int i = blockIdx.x * 256 + threadIdx.x;
    int v = (i < NNODE) ? cnt[i] : 0;
    sh[threadIdx.x] = v;
    __syncthreads();
    for (int o = 1; o < 256; o <<= 1) {
        int x = (threadIdx.x >= o) ? sh[threadIdx.x - o] : 0;
        __syncthreads();
        sh[threadIdx.x] += x;
        __syncthreads();
    }
    if (i < NNODE) rowptr[i] = bsum[blockIdx.x] + sh[threadIdx.x] - v;  // exclusive
    if (i == NNODE - 1) rowptr[NNODE] = E;
}

// ---------------- scatter edges into CSR; dinv computed inline from deg ----------------
__global__ void scatter_edges(const int* __restrict__ row, const int* __restrict__ col,
                              const float* __restrict__ w, const float* __restrict__ deg,
                              const int* __restrict__ rowptr, int* __restrict__ fill,
                              int* __restrict__ ecol, float* __restrict__ eval, int E) {
    int e = blockIdx.x * 256 + threadIdx.x;
    if (e < E) {
        int r = row[e], c = col[e];
        int pos = rowptr[r] + atomicAdd(&fill[r], 1);
        ecol[pos] = c;
        eval[pos] = rsqrtf(deg[r] + 1.0f) * w[e] * rsqrtf(deg[c] + 1.0f);
    }
}

// ---------------- batched prep: 5 weight transposes + x f32->bf16 in ONE kernel --------
__device__ __forceinline__ void tr32(float (*t)[33], const float* __restrict__ W,
                                     short* __restrict__ Wt, int K, int N, int kb, int nb) {
    int tx = threadIdx.x & 31, ty = threadIdx.x >> 5;     // 32 x 8
#pragma unroll
    for (int i = 0; i < 32; i += 8)
        if (kb + ty + i < K && nb + tx < N)
            t[ty + i][tx] = W[(size_t)(kb + ty + i) * N + nb + tx];
    __syncthreads();
#pragma unroll
    for (int i = 0; i < 32; i += 8)
        if (nb + ty + i < N && kb + tx < K)
            Wt[(size_t)(nb + ty + i) * K + kb + tx] = f2bf(t[tx][ty + i]);
}

__global__ __launch_bounds__(256) void prep_batched(const float* __restrict__ W1,
                                                    const float* __restrict__ W2,
                                                    const float* __restrict__ W3,
                                                    const float* __restrict__ Wmu,
                                                    const float* __restrict__ Wlv,
                                                    const float* __restrict__ x,
                                                    short* __restrict__ W1t,
                                                    short* __restrict__ W2t,
                                                    short* __restrict__ W3t,
                                                    short* __restrict__ Wmut,
                                                    short* __restrict__ Wlvt,
                                                    short* __restrict__ xb) {
    __shared__ float t[32][33];
    int bid = blockIdx.x;
    if (bid < 512) {                              // W1: K=512, N=1024 (32 x 16 blocks)
        tr32(t, W1, W1t, FIN, H1DIM, (bid >> 5) * 32, (bid & 31) * 32);
    } else if (bid < 1024) {                      // W2: K=1024, N=512 (16 x 32)
        int b = bid - 512;
        tr32(t, W2, W2t, H1DIM, H2DIM, (b >> 4) * 32, (b & 15) * 32);
    } else if (bid < 1152) {                      // W3: K=512, N=256 (8 x 16)
        int b = bid - 1024;
        tr32(t, W3, W3t, H2DIM, H3DIM, (b >> 3) * 32, (b & 7) * 32);
    } else if (bid < 1280) {                      // Wmu: K=256, N=512 (16 x 8)
        int b = bid - 1152;
        tr32(t, Wmu, Wmut, H3DIM, HDIM, (b >> 4) * 32, (b & 15) * 32);
    } else if (bid < 1408) {                      // Wlv
        int b = bid - 1280;
        tr32(t, Wlv, Wlvt, H3DIM, HDIM, (b >> 4) * 32, (b & 15) * 32);
    } else {                                      // x convert: 15000 blocks of 256 float4
        int i = (bid - 1408) * 256 + threadIdx.x; // i < 3,840,000
        float4 v = ((const float4*)x)[i];
        s16x4 s = { f2bf(v.x), f2bf(v.y), f2bf(v.z), f2bf(v.w) };
        *(s16x4*)(xb + (size_t)i * 4) = s;
    }
}

// ---------------- CSR SpMM on bf16 rows; 4x-unrolled edge loop; deg-inline dinv --------
template <int F, bool FUSE>
__global__ __launch_bounds__(256) void spmm_bf16(const int* __restrict__ rowptr,
                                                 const int* __restrict__ ecol,
                                                 const float* __restrict__ eval,
                                                 const float* __restrict__ deg,
                                                 const short* __restrict__ h,
                                                 const float* __restrict__ bias,
                                                 short* __restrict__ out) {
    constexpr int NE = F / 64;               // 512->8, 256->4
    int lane = threadIdx.x & 63;
    int r = blockIdx.x * 4 + (threadIdx.x >> 6);
    if (r >= NNODE) return;
    float dd = 1.0f / (deg[r] + 1.0f);       // dinv^2 (<=2ulp vs rsqrtf^2; absorbed by bf16)
    float acc[NE];
    {
        const short* p = h + (size_t)r * F + lane * NE;
        if constexpr (NE == 8) {
            s16x8 v = *(const s16x8*)p;
#pragma unroll
            for (int j = 0; j < 8; ++j) acc[j] = dd * bf2f(v[j]);
        } else {
            s16x4 v = *(const s16x4*)p;
#pragma unroll
            for (int j = 0; j < 4; ++j) acc[j] = dd * bf2f(v[j]);
        }
    }
    int e0 = rowptr[r], e1 = rowptr[r + 1];
    int e = e0;
    for (; e + 4 <= e1; e += 4) {
        int   c0 = ecol[e],     c1 = ecol[e + 1], c2 = ecol[e + 2], c3 = ecol[e + 3];
        float w0 = eval[e],     w1 = eval[e + 1], w2 = eval[e + 2], w3 = eval[e + 3];
        const short* p0 = h + (size_t)c0 * F + lane * NE;
        const short* p1 = h + (size_t)c1 * F + lane * NE;
        const short* p2 = h + (size_t)c2 * F + lane * NE;
        const short* p3 = h + (size_t)c3 * F + lane * NE;
        if constexpr (NE == 8) {
            s16x8 v0 = *(const s16x8*)p0;
            s16x8 v1 = *(const s16x8*)p1;
            s16x8 v2 = *(const s16x8*)p2;
            s16x8 v3 = *(const s16x8*)p3;
#pragma unroll
            for (int j = 0; j < 8; ++j) acc[j] = fmaf(w0, bf2f(v0[j]), acc[j]);
#pragma unroll
            for (int j = 0; j < 8; ++j) acc[j] = fmaf(w1, bf2f(v1[j]), acc[j]);
#pragma unroll
            for (int j = 0; j < 8; ++j) acc[j] = fmaf(w2, bf2f(v2[j]), acc[j]);
#pragma unroll
            for (int j = 0; j < 8; ++j) acc[j] = fmaf(w3, bf2f(v3[j]), acc[j]);
        } else {
            s16x4 v0 = *(const s16x4*)p0;
            s16x4 v1 = *(const s16x4*)p1;
            s16x4 v2 = *(const s16x4*)p2;
            s16x4 v3 = *(const s16x4*)p3;
#pragma unroll
            for (int j = 0; j < 4; ++j) acc[j] = fmaf(w0, bf2f(v0[j]), acc[j]);
#pragma unroll
            for (int j = 0; j < 4; ++j) acc[j] = fmaf(w1, bf2f(v1[j]), acc[j]);
#pragma unroll
            for (int j = 0; j < 4; ++j) acc[j] = fmaf(w2, bf2f(v2[j]), acc[j]);
#pragma unroll
            for (int j = 0; j < 4; ++j) acc[j] = fmaf(w3, bf2f(v3[j]), acc[j]);
        }
    }
    for (; e < e1; ++e) {
        int c = ecol[e];
        float nw = eval[e];
        const short* p = h + (size_t)c * F + lane * NE;
        if constexpr (NE == 8) {
            s16x8 v = *(const s16x8*)p;
#pragma unroll
            for (int j = 0; j < 8; ++j) acc[j] = fmaf(nw, bf2f(v[j]), acc[j]);
        } else {
            s16x4 v = *(const s16x4*)p;
#pragma unroll
            for (int j = 0; j < 4; ++j) acc[j] = fmaf(nw, bf2f(v[j]), acc[j]);
        }
    }
    short* o = out + (size_t)r * F + lane * NE;
    if (FUSE) {
        const float* bp = bias + lane * NE;
        float ss = 0.f;
#pragma unroll
        for (int j = 0; j < NE; ++j) { acc[j] += bp[j]; ss += acc[j] * acc[j]; }
#pragma unroll
        for (int off = 32; off; off >>= 1) ss += __shfl_xor(ss, off);
        float rinv = 1.0f / fmaxf(sqrtf(ss), 1e-12f);
#pragma unroll
        for (int j = 0; j < NE; ++j) acc[j] = fmaxf(acc[j] * rinv, 0.f);
    }
    if constexpr (NE == 8) {
        s16x8 s;
#pragma unroll
        for (int j = 0; j < 8; ++j) s[j] = f2bf(acc[j]);
        *(s16x8*)o = s;
    } else {
        s16x4 s;
#pragma unroll
        for (int j = 0; j < 4; ++j) s[j] = f2bf(acc[j]);
        *(s16x4*)o = s;
    }
}

// ---------------- stage one 64-wide K-tile (256 A-rows + BN B-rows) into LDS -----------
// linear LDS dest (rule #21), T2 pre-swizzled global source column. NBCH = BN/64.
#define STAGE_TILE(buf_, kt_)                                                              \
  {                                                                                        \
    const int k0_ = (kt_) << 6;                                                            \
    _Pragma("unroll")                                                                      \
    for (int i_ = 0; i_ < 4; ++i_) {                                                       \
      int c_ = i_ * 8 + w;                                                                 \
      int tr_ = c_ * 8 + srow;                                                             \
      __builtin_amdgcn_global_load_lds(                                                    \
          (const __attribute__((address_space(1))) void*)(A + (size_t)(m0 + tr_) * K + k0_ + scol), \
          (__attribute__((address_space(3))) void*)(&sA[buf_][c_ * 512]), 16, 0, 0);       \
    }                                                                                      \
    _Pragma("unroll")                                                                      \
    for (int i_ = 0; i_ < NBCH; ++i_) {                                                    \
      int c_ = i_ * 8 + w;                                                                 \
      int tr_ = c_ * 8 + srow;                                                             \
      __builtin_amdgcn_global_load_lds(                                                    \
          (const __attribute__((address_space(1))) void*)(Bt + (size_t)(n0 + tr_) * K + k0_ + scol), \
          (__attribute__((address_space(3))) void*)(&sB[buf_][c_ * 512]), 16, 0, 0);       \
    }                                                                                      \
  }

// ---------------- bf16 MFMA GEMM: C[M][N] = A[118*256][K] * Bt[N][K]^T ------------------
// BM=256 fixed; BN templated {256,128}. BN=256: 8 waves 2M x 4N, 128x64/wave (high
// MFMA/ds_read ratio 2.67, 128KB LDS) — use when grid >= 2/CU rounds are acceptable.
// BN=128: 8 waves 4M x 2N, 64x64/wave (ratio 2.0, 96KB LDS) — doubles grid for small N
// (GEMM3 N=256: 118 -> 236 blocks = 46% -> 92% CU coverage).
// 2-phase dbuf: STAGE(next) -> ds_read+MFMA(cur) -> one barrier. T2 swizzle; m204
// bijective XCD swizzle; setprio around MFMA cluster.
// EPI: 0 plain(+bias) | 1 bias+ReLU+row-SS atomics | 2 row-scale rinv(ssbuf) | 3 dual split
template <typename OutT, bool ADD_BIAS, int EPI, int BN>
__global__ __launch_bounds__(512) void gemm_bf16(const short* __restrict__ A,
                                                 const short* __restrict__ Bt,
                                                 const float* __restrict__ bias,
                                                 const float* __restrict__ bias2,
                                                 OutT* __restrict__ C,
                                                 float* __restrict__ C2,
                                                 float* __restrict__ ssbuf,
                                                 int M, int N, int K) {
    constexpr int NBCH  = BN / 64;            // B stage chunk-groups: 4 or 2
    constexpr int WROWS = (BN == 256) ? 128 : 64;  // per-wave output rows
    constexpr int FMN   = WROWS / 16;         // 8 or 4
    __shared__ short sA[2][256 * 64];
    __shared__ short sB[2][BN * 64];
    const int tid = threadIdx.x;
    const int lane = tid & 63;
    const int w = tid >> 6;                   // wave 0..7
    const int wm = (BN == 256) ? (w >> 2) : (w >> 1);
    const int wn = (BN == 256) ? (w & 3) : (w & 1);

    // ---- m204 bijective XCD swizzle over nwg blocks ----
    const int nwg = gridDim.x;
    const int orig = blockIdx.x;
    const int q = nwg >> 3, rr = nwg & 7;
    const int xcd = orig & 7;
    const int base = (xcd < rr) ? xcd * (q + 1) : rr * (q + 1) + (xcd - rr) * q;
    const int wgid = base + (orig >> 3);
    const int nx = N / BN;                    // N-blocks (power of 2)
    const int lg = __builtin_ctz(nx);
    const int pid = wgid >> lg;               // M-panel (256 rows)
    const int cblk = wgid & (nx - 1);
    const int m0 = pid << 8;
    const int n0 = cblk * BN;

    const int srow = lane >> 3;               // 0..7
    const int scol = ((lane & 7) ^ srow) * 8; // T2 pre-swizzled source col

    f32x4 acc[FMN][4] = {};

    const int lrow = lane & 15;
    const int jhi = lane >> 4;                // 0..3

    const int nkt = K >> 6;
    int cur = 0;
    STAGE_TILE(0, 0);
    __syncthreads();                          // drains vmcnt(0): buf0 ready

    for (int kt = 0; kt < nkt; ++kt) {
        if (kt + 1 < nkt) STAGE_TILE(cur ^ 1, kt + 1);   // overlaps compute below

        s16x8 bfr[4][2];
#pragma unroll
        for (int fn = 0; fn < 4; ++fn) {
            int lr = wn * 64 + fn * 16 + lrow;
            const short* bptr = &sB[cur][lr * 64];
            int sl0 = jhi ^ (lr & 7);
            bfr[fn][0] = *(const s16x8*)&bptr[sl0 << 3];
            bfr[fn][1] = *(const s16x8*)&bptr[(sl0 ^ 4) << 3];
        }
        __builtin_amdgcn_s_setprio(1);
#pragma unroll
        for (int fm = 0; fm < FMN; ++fm) {
            int lr = wm * WROWS + fm * 16 + lrow;
            const short* aptr = &sA[cur][lr * 64];
            int sl0 = jhi ^ (lr & 7);
            s16x8 a0 = *(const s16x8*)&aptr[sl0 << 3];
            s16x8 a1 = *(const s16x8*)&aptr[(sl0 ^ 4) << 3];
#pragma unroll
            for (int fn = 0; fn < 4; ++fn) {
                acc[fm][fn] = __builtin_amdgcn_mfma_f32_16x16x32_bf16(a0, bfr[fn][0], acc[fm][fn], 0, 0, 0);
                acc[fm][fn] = __builtin_amdgcn_mfma_f32_16x16x32_bf16(a1, bfr[fn][1], acc[fm][fn], 0, 0, 0);
            }
        }
        __builtin_amdgcn_s_setprio(0);
        __syncthreads();                      // retires cur reads + drains stage of cur^1
        cur ^= 1;
    }

    const int crow = (lane >> 4) * 4;
    const int ccol = lane & 15;

    if constexpr (EPI == 1) {
        float ssl[FMN][4] = {};
#pragma unroll
        for (int fm = 0; fm < FMN; ++fm) {
#pragma unroll
            for (int fn = 0; fn < 4; ++fn) {
                int n = n0 + wn * 64 + fn * 16 + ccol;
                float b = bias[n];
#pragma unroll
                for (int r = 0; r < 4; ++r) {
                    float o = acc[fm][fn][r] + b;
                    ssl[fm][r] += o * o;
                    int m = m0 + wm * WROWS + fm * 16 + crow + r;
                    if (m < M) C[(size_t)m * N + n] = (OutT)f2bf(fmaxf(o, 0.f));
                }
            }
        }
#pragma unroll
        for (int fm = 0; fm < FMN; ++fm)
#pragma unroll
            for (int r = 0; r < 4; ++r) {
                float v = ssl[fm][r];
                v += __shfl_xor(v, 1); v += __shfl_xor(v, 2);
                v += __shfl_xor(v, 4); v += __shfl_xor(v, 8);
                int m = m0 + wm * WROWS + fm * 16 + crow + r;
                if (ccol == 0 && m < M) atomicAdd(&ssbuf[m], v);
            }
    } else if constexpr (EPI == 2) {
#pragma unroll
        for (int fm = 0; fm < FMN; ++fm) {
#pragma unroll
            for (int r = 0; r < 4; ++r) {
                int m = m0 + wm * WROWS + fm * 16 + crow + r;
                if (m >= M) continue;
                float sc = 1.0f / fmaxf(sqrtf(ssbuf[m]), 1e-12f);
#pragma unroll
                for (int fn = 0; fn < 4; ++fn) {
                    int n = n0 + wn * 64 + fn * 16 + ccol;
                    C[(size_t)m * N + n] = (OutT)f2bf(acc[fm][fn][r] * sc);
                }
            }
        }
    } else if constexpr (EPI == 3) {
        const int half = N >> 1;
#pragma unroll
        for (int fm = 0; fm < FMN; ++fm) {
#pragma unroll
            for (int fn = 0; fn < 4; ++fn) {
                int n = n0 + wn * 64 + fn * 16 + ccol;
                bool hi = n >= half;
                float b = hi ? bias2[n - half] : bias[n];
                float* Cp = hi ? C2 : (float*)C;
                int nc = hi ? (n - half) : n;
#pragma unroll
                for (int r = 0; r < 4; ++r) {
                    int m = m0 + wm * WROWS + fm * 16 + crow + r;
                    if (m < M) Cp[(size_t)m * half + nc] = acc[fm][fn][r] + b;
                }
            }
        }
    } else {
#pragma unroll
        for (int fm = 0; fm < FMN; ++fm) {
#pragma unroll
            for (int fn = 0; fn < 4; ++fn) {
                int n = n0 + wn * 64 + fn * 16 + ccol;
                float b = ADD_BIAS ? bias[n] : 0.f;
#pragma unroll
                for (int r = 0; r < 4; ++r) {
                    int m = m0 + wm * WROWS + fm * 16 + crow + r;
                    if (m < M) {
                        float o = acc[fm][fn][r] + b;
                        if constexpr (sizeof(OutT) == 2) C[(size_t)m * N + n] = (OutT)f2bf(o);
                        else                             C[(size_t)m * N + n] = o;
                    }
                }
            }
        }
    }
}

// ---------------- pooling stage 1: 1875 blocks x 8 row-pairs ----------------
__global__ __launch_bounds__(256) void pool_partial(const float* __restrict__ mu,
                                                    const float* __restrict__ lv,
                                                    const uint32_t* __restrict__ beta_p,
                                                    float* __restrict__ pmax,
                                                    float* __restrict__ psum) {
    uint32_t bb = beta_p[0];
    float beta = (bb & 0x7F800000u) ? __uint_as_float(bb) : (float)(int)bb;
    int b = blockIdx.x;
    int r0 = b * PP_ROWS;
    int r1 = min(r0 + PP_ROWS, HALF_ROWS);
    int c = threadIdx.x * 2;
    float m0 = -INFINITY, m1 = -INFINITY, s0 = 0.f, s1 = 0.f;
    for (int r = r0; r < r1; ++r) {
        size_t ia = (size_t)r * HDIM + c;
        size_t ib = (size_t)(r + HALF_ROWS) * HDIM + c;
        float2 mua = *(const float2*)&mu[ia];
        float2 lva = *(const float2*)&lv[ia];
        float2 mub = *(const float2*)&mu[ib];
        float2 lvb = *(const float2*)&lv[ib];
        uint32_t idx0 = (uint32_t)r * 512u + (uint32_t)c;
        uint32_t xa0 = idx0,     ya0 = idx0 + HALF_ELEMS;
        uint32_t xa1 = idx0 + 1, ya1 = idx0 + 1 + HALF_ELEMS;
        threefry2x32(0u, 42u, xa0, ya0);
        threefry2x32(0u, 42u, xa1, ya1);
        float za0 = mua.x + 0.01f * jax_normal(xa0) * __expf(0.5f * beta * lva.x);
        float zb0 = mub.x + 0.01f * jax_normal(ya0) * __expf(0.5f * beta * lvb.x);
        float za1 = mua.y + 0.01f * jax_normal(xa1) * __expf(0.5f * beta * lva.y);
        float zb1 = mub.y + 0.01f * jax_normal(ya1) * __expf(0.5f * beta * lvb.y);
        m0 = fmaxf(m0, fmaxf(za0, zb0)); s0 += za0 + zb0;
        m1 = fmaxf(m1, fmaxf(za1, zb1)); s1 += za1 + zb1;
    }
    pmax[(size_t)b * HDIM + c]     = m0;
    pmax[(size_t)b * HDIM + c + 1] = m1;
    psum[(size_t)b * HDIM + c]     = s0;
    psum[(size_t)b * HDIM + c + 1] = s1;
}

// ---------------- pooling stage 2: 1875 -> 63 partials ----------------
__global__ __launch_bounds__(256) void pool_mid(const float* __restrict__ pmax,
                                                const float* __restrict__ psum,
                                                float* __restrict__ pmax2,
                                                float* __restrict__ psum2) {
    int g = blockIdx.x;
    int b0 = g * 30;
    int b1 = min(b0 + 30, PP_BLOCKS);
#pragma unroll
    for (int pass = 0; pass < 2; ++pass) {
        int c = threadIdx.x + pass * 256;
        float m = -INFINITY, s = 0.f;
        for (int b = b0; b < b1; ++b) {
            m = fmaxf(m, pmax[(size_t)b * HDIM + c]);
            s += psum[(size_t)b * HDIM + c];
        }
        pmax2[(size_t)g * HDIM + c] = m;
        psum2[(size_t)g * HDIM + c] = s;
    }
}

// ---------------- decoder stage 1: fused pool_final + dense_partial --------------------
__global__ __launch_bounds__(256) void dec1(const float* __restrict__ pmax2,
                                            const float* __restrict__ psum2,
                                            const float* __restrict__ W,
                                            float* __restrict__ part) {
    __shared__ float sin_[128];
    int by = blockIdx.y;
    if (threadIdx.x < 128) {
        int c = by * 128 + threadIdx.x;               // 0..1023
        float v;
        if (c < HDIM) {
            float m = -INFINITY;
            for (int b = 0; b < PM_BLOCKS; ++b) m = fmaxf(m, pmax2[(size_t)b * HDIM + c]);
            v = m;
        } else {
            int cc = c - HDIM;
            float s = 0.f;
            for (int b = 0; b < PM_BLOCKS; ++b) s += psum2[(size_t)b * HDIM + cc];
            v = s / 30000.0f;
        }
        sin_[threadIdx.x] = v;
    }
    __syncthreads();
    int j = blockIdx.x * 256 + threadIdx.x;
    float acc = 0.f;
#pragma unroll 8
    for (int i = 0; i < 128; ++i)
        acc = fmaf(sin_[i], W[(size_t)(by * 128 + i) * 1024 + j], acc);
    part[(size_t)by * 1024 + j] = acc;
}

// ---------------- decoder stage 2: fused dense_final(relu) + dense_partial -------------
__global__ __launch_bounds__(256) void dec2(const float* __restrict__ part,
                                            const float* __restrict__ bd1,
                                            const float* __restrict__ W,
                                            float* __restrict__ part2) {
    __shared__ float sh[128];
    int by = blockIdx.y;
    if (threadIdx.x < 128) {
        int j2 = by * 128 + threadIdx.x;
        float v = bd1[j2];
#pragma unroll
        for (int s = 0; s < 8; ++s) v += part[(size_t)s * 1024 + j2];
        sh[threadIdx.x] = fmaxf(v, 0.f);
    }
    __syncthreads();
    int j = blockIdx.x * 256 + threadIdx.x;
    float acc = 0.f;
#pragma unroll 8
    for (int i = 0; i < 128; ++i)
        acc = fmaf(sh[i], W[(size_t)(by * 128 + i) * 1024 + j], acc);
    part2[(size_t)by * 1024 + j] = acc;
}

__global__ void dense_final(const float* __restrict__ part, const float* __restrict__ bias,
                            float* __restrict__ out) {
    int j = blockIdx.x * 256 + threadIdx.x;
    float acc = bias[j];
#pragma unroll
    for (int s = 0; s < 8; ++s) acc += part[(size_t)s * 1024 + j];
    out[j] = 1.0f / (1.0f + __expf(-acc));
}

// ---------------- launch ----------------
extern "C" void kernel_launch(void* const* d_in, const int* in_sizes, int n_in,
                              void* d_out, int out_size, void* d_ws, size_t ws_size,
                              hipStream_t stream) {
    const float* x   = (const float*)d_in[0];
    const int*   ei  = (const int*)d_in[1];
    const float* ew  = (const float*)d_in[2];
    const uint32_t* beta = (const uint32_t*)d_in[3];
    const float* W1  = (const float*)d_in[4];
    const float* b1  = (const float*)d_in[5];
    const float* W2  = (const float*)d_in[6];
    const float* b2  = (const float*)d_in[7];
    const float* W3  = (const float*)d_in[8];
    const float* b3  = (const float*)d_in[9];
    const float* Wmu = (const float*)d_in[10];
    const float* bmu = (const float*)d_in[11];
    const float* Wlv = (const float*)d_in[12];
    const float* blv = (const float*)d_in[13];
    const float* Wd1 = (const float*)d_in[14];
    const float* bd1 = (const float*)d_in[15];
    const float* Wd2 = (const float*)d_in[16];
    const float* bd2 = (const float*)d_in[17];

    const int E = in_sizes[2];            // 300000
    const int M = NNODE;

    float* out    = (float*)d_out;
    float* mu_out = out + 1024;                           // [30000,512]
    float* lv_out = out + 1024 + (size_t)M * HDIM;        // [30000,512]

    // ---------------- workspace layout (bytes); no trailing backslashes in comments ----
    char* Wp = (char*)d_ws;
    short* slotA  = (short*)(Wp);                         // 61,603,840 B
    short* slotB  = (short*)(Wp + 61603840);              // 61,603,840 B
    short* xb     = (short*)(Wp + 123207680);             // 30,720,000 B
    short* W1t    = (short*)(Wp + 154009600);             // 1024x512
    short* W2t    = (short*)(Wp + 155058176);             // 512x1024
    short* W3t    = (short*)(Wp + 156106752);             // 256x512
    short* Wmut   = (short*)(Wp + 156368896);             // 512x256 (Wlvt MUST follow)
    short* Wlvt   = (short*)(Wp + 156631040);             // 512x256 = Wmut + 262144 B
    float* deg    = (float*)(Wp + 156893184);             // 120,000 B (memset group start)
    float* spare  = (float*)(Wp + 157013184);             // 120,000 B (unused)
    int*   cnt    = (int*)  (Wp + 157133184);             // 120,000 B
    int*   fill   = (int*)  (Wp + 157253184);             // 120,000 B
    float* ssbuf  = (float*)(Wp + 157373184);             // 120,000 B (memset group end)
    int*   rowptr = (int*)  (Wp + 157493184);             // 120,004 B
    int*   ecol   = (int*)  (Wp + 157613188);             // 1,200,000 B
    float* eval   = (float*)(Wp + 158813188);             // 1,200,000 B
    float* pmax   = (float*)(Wp + 160013188);             // 1875*512*4 = 3,840,000 B
    float* psum   = (float*)(Wp + 163853188);             // 3,840,000 B
    float* pmax2  = (float*)(Wp + 167693188);             // 63*512*4 = 129,024 B
    float* psum2  = (float*)(Wp + 167822212);             // 129,024 B
    float* dpart  = (float*)(Wp + 167951236);             // 32,768 B
    float* dpart2 = (float*)(Wp + 167984004);             // 32,768 B (ends ~168.0 MB)
    int*   bsum   = (int*)pmax;                           // scan scratch; pmax unused until pooling
    (void)spare;

    const int* row = ei;
    const int* col = ei + E;

    // 1) one memset for deg|spare|cnt|fill|ssbuf
    hipMemsetAsync(deg, 0, 600000, stream);

    deg_cnt_kernel<<<(E + 255) / 256, 256, 0, stream>>>(row, ew, deg, cnt, E);
    rp_blocksum<<<NSCAN, 256, 0, stream>>>(cnt, bsum);
    rp_scan<<<1, 128, 0, stream>>>(bsum, NSCAN);
    rp_write<<<NSCAN, 256, 0, stream>>>(cnt, bsum, rowptr, E);
    scatter_edges<<<(E + 255) / 256, 256, 0, stream>>>(row, col, ew, deg, rowptr, fill,
                                                       ecol, eval, E);

    // 2) batched prep: 5 transposes + x convert in one kernel (1408 + 15000 blocks)
    prep_batched<<<16408, 256, 0, stream>>>(W1, W2, W3, Wmu, Wlv, x,
                                            W1t, W2t, W3t, Wmut, Wlvt, xb);

    const int SPMM_GRID = (M + 3) / 4;

    // 3) layer 1: AXb = A_hat@xb (slotA); relu_h1 + row-ss = AXb@W1t+b1 (slotB, EPI1)
    spmm_bf16<512, false><<<SPMM_GRID, 256, 0, stream>>>(rowptr, ecol, eval, deg, xb,
                                                         nullptr, slotA);
    gemm_bf16<short, true, 1, 256><<<(H1DIM / 256) * NPANEL, 512, 0, stream>>>(
        slotA, W1t, b1, nullptr, slotB, nullptr, ssbuf, M, H1DIM, FIN);

    // 4) layer 2: h2 = (relu_h1 @ W2t) * rinv[row] (slotA, EPI2 inline rsqrt);
    //    out2 = fused spmm (slotB)
    gemm_bf16<short, false, 2, 256><<<(H2DIM / 256) * NPANEL, 512, 0, stream>>>(
        slotB, W2t, nullptr, nullptr, slotA, nullptr, ssbuf, M, H2DIM, H1DIM);
    spmm_bf16<512, true><<<SPMM_GRID, 256, 0, stream>>>(rowptr, ecol, eval, deg, slotA,
                                                        b2, slotB);

    // 5) layer 3: h3 = out2@W3t (slotA, BN=128: 236 blocks = 92% CU coverage vs 46%);
    //    out3 = fused spmm (slotB)
    gemm_bf16<short, false, 0, 128><<<(H3DIM / 128) * NPANEL, 512, 0, stream>>>(
        slotB, W3t, nullptr, nullptr, slotA, nullptr, nullptr, M, H3DIM, H2DIM);
    spmm_bf16<256, true><<<SPMM_GRID, 256, 0, stream>>>(rowptr, ecol, eval, deg, slotA,
                                                        b3, slotB);

    // 6) mu / logvar in ONE GEMM (Bt = [Wmut;Wlvt] contiguous, N=1024, split epilogue)
    gemm_bf16<float, true, 3, 256><<<((2 * HDIM) / 256) * NPANEL, 512, 0, stream>>>(
        slotB, Wmut, bmu, blv, mu_out, lv_out, nullptr, M, 2 * HDIM, H3DIM);

    // 7) pooling (JAX-exact noise): partial -> mid; final fused into dec1
    pool_partial<<<PP_BLOCKS, 256, 0, stream>>>(mu_out, lv_out, beta, pmax, psum);
    pool_mid<<<PM_BLOCKS, 256, 0, stream>>>(pmax, psum, pmax2, psum2);

    // 8) decoder: dec1 (pool_final+partial), dec2 (relu-final+partial), final sigmoid
    dec1<<<dim3(4, 8), 256, 0, stream>>>(pmax2, psum2, Wd1, dpart);
    dec2<<<dim3(4, 8), 256, 0, stream>>>(dpart, bd1, Wd2, dpart2);
    dense_final<<<4, 256, 0, stream>>>(dpart2, bd2, out);
}